// Round 1
// baseline (1007.445 us; speedup 1.0000x reference)
//
#include <hip/hip_runtime.h>
#include <hip/hip_bf16.h>

// UniqueEq3Net: conv stack -> e(640,64); t = e⊗e⊗e never materialized.
// Layer1: h[b,i,j,k,o] = relu( sum_d e_k[d]*G_ij[d,o] + const_ij[o] )
//   G_ij = (e_i*e_j)⊙W0 + e_j⊙(S⊙W1) + e_i⊙(S⊙W2) + S^2⊙W4   (per b)
//   const_ij[o] = Q3[i,j,o] + P5[j,o] + P6[i,o] + c0[o]
// Layer2 needs axis reductions of h -> 3 recompute passes (no global atomics):
//   mode0 block=(b,j) loop i: si2 (LDS acc), sk2 (direct store)
//   mode1 block=(b,i) loop j: sj2 (LDS acc)
//   mode2 block=(b,j) loop i: h -> MFMA with W'0 + addends -> relu -> out_part
// All heavy GEMMs: v_mfma_f32_16x16x32_bf16 (M=48 padded, N=64/32, K=64).

typedef unsigned short u16;
typedef __attribute__((ext_vector_type(8))) short bf8_t;   // 8 bf16 (4 VGPRs)
typedef __attribute__((ext_vector_type(4))) float f4_t;

#define LSTR 72   // padded LDS row stride (u16) for MFMA frag b128 reads: 144B rows

__device__ inline u16 f2bf(float f){
  union { float f; unsigned u; } v; v.f = f;
  unsigned r = v.u + 0x7fffu + ((v.u >> 16) & 1u);
  return (u16)(r >> 16);
}
__device__ inline float bflo(unsigned u){ union { unsigned x; float f; } v; v.x = u << 16; return v.f; }
__device__ inline float bfhi(unsigned u){ union { unsigned x; float f; } v; v.x = u & 0xffff0000u; return v.f; }
__device__ inline unsigned pack2(float a, float b){ return (unsigned)f2bf(a) | ((unsigned)f2bf(b) << 16); }

// ---------------- conv1 + pool -> z1 (640,32,12,12) ----------------
__global__ __launch_bounds__(256) void kconv1(const float* __restrict__ x, const float* __restrict__ w1,
                                              const float* __restrict__ b1, float* __restrict__ z1){
  __shared__ float simg[784];
  __shared__ float sw[800];
  __shared__ float sb[32];
  int img = blockIdx.x, tid = threadIdx.x;
  for (int i = tid; i < 784; i += 256) simg[i] = x[img*784 + i];
  for (int i = tid; i < 800; i += 256) sw[i] = w1[i];
  if (tid < 32) sb[tid] = b1[tid];
  __syncthreads();
  for (int idx = tid; idx < 4608; idx += 256){
    int c = idx / 144, p = idx % 144, py = p / 12, px = p % 12;
    const float* wc = &sw[c*25];
    float mx = -1e30f;
    #pragma unroll
    for (int sy = 0; sy < 2; ++sy)
    #pragma unroll
    for (int sx = 0; sx < 2; ++sx){
      int y0 = 2*py + sy, x0 = 2*px + sx;
      float s = sb[c];
      #pragma unroll
      for (int dy = 0; dy < 5; ++dy)
      #pragma unroll
      for (int dx = 0; dx < 5; ++dx)
        s += simg[(y0+dy)*28 + x0+dx] * wc[dy*5+dx];
      mx = fmaxf(mx, s);
    }
    z1[(size_t)img*4608 + idx] = fmaxf(mx, 0.f);
  }
}

// ---------------- conv2 + pool + fc -> e (640,64) fp32 + bf16 ----------------
__global__ __launch_bounds__(256) void kconv2(const float* __restrict__ z1, const float* __restrict__ w2,
                                              const float* __restrict__ b2, const float* __restrict__ fcw,
                                              const float* __restrict__ fcb,
                                              float* __restrict__ e_f, u16* __restrict__ e_b){
  __shared__ float sz1[4608];
  __shared__ float swc[6400];   // 8 out-channels x 32 x 25
  __shared__ float sz2[1024];
  __shared__ float spart[1024]; // [pos][tid]
  int img = blockIdx.x, tid = threadIdx.x;
  for (int i = tid; i < 4608; i += 256) sz1[i] = z1[(size_t)img*4608 + i];
  int half = tid >> 7, rem = tid & 127;
  int c2l = rem >> 4, p = rem & 15, py = p >> 2, px = p & 3;
  int ybase = 2*py, xbase = 2*px;
  for (int ch = 0; ch < 8; ++ch){
    __syncthreads();
    for (int i = tid; i < 6400; i += 256) swc[i] = w2[ch*6400 + i];
    __syncthreads();
    float s0=0.f, s1=0.f, s2=0.f, s3=0.f;
    for (int c = half*16; c < half*16 + 16; ++c){
      float patch[36];
      const float* zz = &sz1[c*144 + ybase*12 + xbase];
      #pragma unroll
      for (int yy = 0; yy < 6; ++yy)
      #pragma unroll
      for (int xx = 0; xx < 6; ++xx) patch[yy*6+xx] = zz[yy*12+xx];
      const float* ww = &swc[c2l*800 + c*25];
      #pragma unroll
      for (int dy = 0; dy < 5; ++dy)
      #pragma unroll
      for (int dx = 0; dx < 5; ++dx){
        float w = ww[dy*5+dx];
        s0 += patch[dy*6+dx]   * w;
        s1 += patch[dy*6+dx+1] * w;
        s2 += patch[(dy+1)*6+dx]   * w;
        s3 += patch[(dy+1)*6+dx+1] * w;
      }
    }
    spart[0*256 + tid] = s0; spart[1*256 + tid] = s1;
    spart[2*256 + tid] = s2; spart[3*256 + tid] = s3;
    __syncthreads();
    if (tid < 128){
      int c2 = ch*8 + (tid >> 4);
      float v0 = spart[0*256 + tid] + spart[0*256 + 128 + tid];
      float v1 = spart[1*256 + tid] + spart[1*256 + 128 + tid];
      float v2 = spart[2*256 + tid] + spart[2*256 + 128 + tid];
      float v3 = spart[3*256 + tid] + spart[3*256 + 128 + tid];
      float mx = fmaxf(fmaxf(v0, v1), fmaxf(v2, v3)) + b2[c2];
      sz2[c2*16 + (tid & 15)] = fmaxf(mx, 0.f);
    }
  }
  __syncthreads();
  if (tid < 64){
    float a = fcb[tid];
    for (int f = 0; f < 1024; ++f) a += sz2[f] * fcw[f*64 + tid];
    a = fmaxf(a, 0.f);
    e_f[img*64 + tid] = a;
    e_b[img*64 + tid] = f2bf(a);
  }
}

// ---------------- per-b precompute: S, Vt(bf16 x4), c0, P5, P6, W2T0 ----------------
__global__ __launch_bounds__(256) void kprep(const float* __restrict__ e_f, const float* __restrict__ e1w,
    const float* __restrict__ e1b, const float* __restrict__ e2w,
    float* __restrict__ Sg, u16* __restrict__ Vt, float* __restrict__ c0,
    float* __restrict__ P5, float* __restrict__ P6, u16* __restrict__ W2T0){
  int b = blockIdx.x, tid = threadIdx.x;
  __shared__ float se[2560];
  __shared__ float S[64], S2[64], S3[64];
  for (int i = tid; i < 2560; i += 256) se[i] = e_f[b*2560 + i];
  __syncthreads();
  if (tid < 64){
    float s = 0.f;
    for (int i = 0; i < 40; ++i) s += se[i*64 + tid];
    S[tid] = s; S2[tid] = s*s; S3[tid] = s*s*s; Sg[b*64 + tid] = s;
  }
  __syncthreads();
  // Vt layout [b][m][o][d] bf16; m: 0=W0^T 1=(S⊙W1)^T 2=(S⊙W2)^T 3=(S²⊙W4)^T
  for (int idx = tid; idx < 16384; idx += 256){
    int m = idx >> 12, rc = idx & 4095, o = rc >> 6, d = rc & 63;
    float v;
    if (m == 0)      v = e1w[d*64 + o];
    else if (m == 1) v = S[d] * e1w[4096  + d*64 + o];
    else if (m == 2) v = S[d] * e1w[8192  + d*64 + o];
    else             v = S2[d] * e1w[16384 + d*64 + o];
    Vt[(size_t)b*16384 + idx] = f2bf(v);
  }
  if (tid < 64){
    float a = e1b[tid];
    for (int d = 0; d < 64; ++d) a += S3[d] * e1w[7*4096 + d*64 + tid];
    c0[b*64 + tid] = a;
  }
  for (int idx = tid; idx < 2560; idx += 256){
    int j = idx >> 6, o = idx & 63;
    float a5 = 0.f, a6 = 0.f;
    for (int d = 0; d < 64; ++d){
      float es = se[j*64 + d] * S2[d];
      a5 += es * e1w[5*4096 + d*64 + o];
      a6 += es * e1w[6*4096 + d*64 + o];
    }
    P5[(b*40+j)*64 + o] = a5;
    P6[(b*40+j)*64 + o] = a6;
  }
  if (b == 0){
    for (int idx = tid; idx < 2048; idx += 256){
      int o = idx >> 6, d = idx & 63;
      W2T0[o*64 + d] = f2bf(e2w[d*32 + o]);   // W'0 transposed, bf16
    }
  }
}

// ---------------- Q3[b,i,j,o] = sum_d (e_i e_j S)[d] W3[d,o] ----------------
__global__ __launch_bounds__(256) void kq3(const float* __restrict__ e_f, const float* __restrict__ Sg,
    const float* __restrict__ e1w, float* __restrict__ Q3){
  int blk = blockIdx.x, b = blk/40, i = blk%40, tid = threadIdx.x;
  __shared__ float w3[4096];
  __shared__ float se[2560];
  __shared__ float t3[64];
  for (int idx = tid; idx < 4096; idx += 256) w3[idx] = e1w[12288 + idx];
  for (int idx = tid; idx < 2560; idx += 256) se[idx] = e_f[b*2560 + idx];
  __syncthreads();
  if (tid < 64) t3[tid] = se[i*64 + tid] * Sg[b*64 + tid];
  __syncthreads();
  for (int idx = tid; idx < 2560; idx += 256){
    int j = idx >> 6, o = idx & 63;
    float a = 0.f;
    for (int d = 0; d < 64; ++d) a += t3[d] * se[j*64 + d] * w3[d*64 + o];
    Q3[((size_t)(b*40+i)*40 + j)*64 + o] = a;
  }
}

// ---------------- the workhorse: h recompute, 3 modes ----------------
__global__ __launch_bounds__(256, 2) void kh(
    int mode,
    const u16* __restrict__ e_b, const u16* __restrict__ Vt,
    const float* __restrict__ Q3, const float* __restrict__ P5, const float* __restrict__ P6,
    const float* __restrict__ c0,
    float* __restrict__ red_out, float* __restrict__ sk2,
    const u16* __restrict__ W2T0,
    const float* __restrict__ A1p, const float* __restrict__ A2t, const float* __restrict__ Cc,
    float* __restrict__ out_part)
{
  __shared__ __align__(16) u16 sU[48*LSTR];     // e rows (padded to 48, zeros)
  __shared__ __align__(16) u16 sV[4*4096];      // 4 bf16 matrices [m][o][d], stride 64
  __shared__ __align__(16) u16 sG[64*LSTR];     // G^T bf16
  __shared__ __align__(16) float sacc[2600];    // si2/sj2 acc (stride 65) OR sH alias
  __shared__ __align__(16) u16 sW2[32*LSTR];    // W'0^T bf16 (mode2)
  __shared__ float sco[64];
  __shared__ float skb[64];
  __shared__ float soacc[32];
  u16* sH = (u16*)sacc;                          // 48*LSTR u16 = 6912B <= 10400B

  const int tid = threadIdx.x;
  const int blk = blockIdx.x;
  const int b = blk / 40, fix = blk % 40;
  const int wave = tid >> 6, lane = tid & 63;
  const int l15 = lane & 15, quad = lane >> 4;

  // stage U (48x64 -> stride 72), rows >=40 zero
  for (int idx = tid; idx < 1536; idx += 256){
    int r = idx >> 5, c = idx & 31;
    unsigned v = (r < 40) ? ((const unsigned*)e_b)[(b*40 + r)*32 + c] : 0u;
    ((unsigned*)(sU + r*LSTR))[c] = v;
  }
  // stage the 4 per-b bf16 matrices (straight copy, stride 64)
  for (int i = tid; i < 2048; i += 256)
    ((uint4*)sV)[i] = ((const uint4*)(Vt + (size_t)b*16384))[i];
  if (mode == 2){
    for (int idx = tid; idx < 1024; idx += 256){
      int o = idx >> 5, c = idx & 31;
      ((unsigned*)(sW2 + o*LSTR))[c] = ((const unsigned*)W2T0)[idx];
    }
    if (tid < 32) soacc[tid] = 0.f;
  } else {
    for (int idx = tid; idx < 2600; idx += 256) sacc[idx] = 0.f;
    if (tid < 64) skb[tid] = 0.f;
  }
  __syncthreads();

  const unsigned* sVu = (const unsigned*)sV;
  for (int l = 0; l < 40; ++l){
    const int i_ = (mode == 1) ? fix : l;
    const int j_ = (mode == 1) ? l : fix;
    // ---- build G^T (bf16) + const row ----
    for (int idx = tid; idx < 2048; idx += 256){
      int o = idx >> 5, d2 = idx & 31;
      unsigned uu = ((const unsigned*)(sU + i_*LSTR))[d2];
      unsigned ju = ((const unsigned*)(sU + j_*LSTR))[d2];
      unsigned w0 = sVu[        o*32 + d2];
      unsigned w1 = sVu[2048 +  o*32 + d2];
      unsigned w2 = sVu[4096 +  o*32 + d2];
      unsigned w4 = sVu[6144 +  o*32 + d2];
      float ui0 = bflo(uu), ui1 = bfhi(uu), uj0 = bflo(ju), uj1 = bfhi(ju);
      float g0 = ui0*uj0*bflo(w0) + uj0*bflo(w1) + ui0*bflo(w2) + bflo(w4);
      float g1 = ui1*uj1*bfhi(w0) + uj1*bfhi(w1) + ui1*bfhi(w2) + bfhi(w4);
      ((unsigned*)(sG + o*LSTR))[d2] = pack2(g0, g1);
    }
    if (tid < 64){
      sco[tid] = Q3[((size_t)(b*40+i_)*40 + j_)*64 + tid]
               + P5[(b*40+j_)*64 + tid] + P6[(b*40+i_)*64 + tid] + c0[b*64 + tid];
    }
    __syncthreads();   // S1

    // ---- layer-1 MFMA: wave w -> o-tile w; m-tiles 0..2 ----
    f4_t acc[3];
    acc[0] = (f4_t){0.f,0.f,0.f,0.f}; acc[1] = acc[0]; acc[2] = acc[0];
    #pragma unroll
    for (int ks = 0; ks < 2; ++ks){
      const int col = ks*32 + quad*8;
      bf8_t bfr = *(const bf8_t*)&sG[(wave*16 + l15)*LSTR + col];
      #pragma unroll
      for (int m = 0; m < 3; ++m){
        bf8_t af = *(const bf8_t*)&sU[(m*16 + l15)*LSTR + col];
        acc[m] = __builtin_amdgcn_mfma_f32_16x16x32_bf16(af, bfr, acc[m], 0, 0, 0);
      }
    }
    const int o1 = wave*16 + l15;
    const float cadd = sco[o1];

    if (mode != 2){
      float ksum = 0.f;
      #pragma unroll
      for (int m = 0; m < 3; ++m){
        #pragma unroll
        for (int r = 0; r < 4; ++r){
          int k = m*16 + quad*4 + r;
          if (k < 40){
            float h = acc[m][r] + cadd;
            h = h > 0.f ? h : 0.f;
            sacc[k*65 + o1] += h;    // unique (k,o) owner per thread
            ksum += h;
          }
        }
      }
      if (mode == 0) atomicAdd(&skb[o1], ksum);
      __syncthreads();   // S2
      if (mode == 0 && tid < 64){
        sk2[((size_t)(b*40+i_)*40 + j_)*64 + tid] = skb[tid];
        skb[tid] = 0.f;
      }
    } else {
      // write h (bf16) for the second MFMA; k>=40 rows zero
      #pragma unroll
      for (int m = 0; m < 3; ++m){
        #pragma unroll
        for (int r = 0; r < 4; ++r){
          int k = m*16 + quad*4 + r;
          float h = acc[m][r] + cadd;
          h = (h > 0.f && k < 40) ? h : 0.f;
          sH[k*LSTR + o1] = f2bf(h);
        }
      }
      __syncthreads();   // SA
      if (wave < 2){
        f4_t y[3];
        y[0] = (f4_t){0.f,0.f,0.f,0.f}; y[1] = y[0]; y[2] = y[0];
        #pragma unroll
        for (int ks = 0; ks < 2; ++ks){
          const int col = ks*32 + quad*8;
          bf8_t bw = *(const bf8_t*)&sW2[(wave*16 + l15)*LSTR + col];
          #pragma unroll
          for (int m = 0; m < 3; ++m){
            bf8_t hf = *(const bf8_t*)&sH[(m*16 + l15)*LSTR + col];
            y[m] = __builtin_amdgcn_mfma_f32_16x16x32_bf16(hf, bw, y[m], 0, 0, 0);
          }
        }
        const int o2 = wave*16 + l15;
        const float ccv = Cc[((size_t)(b*40+i_)*40 + j_)*32 + o2];
        float psum = 0.f;
        #pragma unroll
        for (int m = 0; m < 3; ++m){
          #pragma unroll
          for (int r = 0; r < 4; ++r){
            int k = m*16 + quad*4 + r;
            if (k < 40){
              float v = y[m][r] + A1p[((size_t)(b*40+j_)*40 + k)*32 + o2]
                                + A2t[((size_t)(b*40+i_)*40 + k)*32 + o2] + ccv;
              psum += v > 0.f ? v : 0.f;
            }
          }
        }
        atomicAdd(&soacc[o2], psum);
      }
      __syncthreads();   // SE
    }
  }
  __syncthreads();
  if (mode == 2){
    if (tid < 32) out_part[(b*40 + fix)*32 + tid] = soacc[tid];
  } else {
    for (int idx = tid; idx < 2560; idx += 256){
      int k = idx >> 6, o = idx & 63;
      red_out[((size_t)(b*40+fix)*40 + k)*64 + o] = sacc[k*65 + o];
    }
  }
}

// ---------------- pair sums + small addends ----------------
__global__ __launch_bounds__(256) void k5a(const float* __restrict__ si2, const float* __restrict__ sj2,
    const float* __restrict__ e2w, const float* __restrict__ e2b,
    float* __restrict__ A4, float* __restrict__ A5, float* __restrict__ A6, float* __restrict__ A7){
  int b = blockIdx.x, tid = threadIdx.x;
  __shared__ float ssij[2560], ssik[2560], ssjk[2560], ss2[64];
  for (int idx = tid; idx < 2560; idx += 256){
    int k = idx >> 6, d = idx & 63;
    float a = 0.f;
    for (int j = 0; j < 40; ++j) a += si2[((size_t)(b*40+j)*40 + k)*64 + d];
    ssij[idx] = a;
  }
  for (int idx = tid; idx < 2560; idx += 256){
    int j = idx >> 6, d = idx & 63;
    float a = 0.f, c = 0.f;
    const float* p = &si2[(size_t)(b*40+j)*2560 + d];
    const float* q = &sj2[(size_t)(b*40+j)*2560 + d];
    for (int k = 0; k < 40; ++k){ a += p[k*64]; c += q[k*64]; }
    ssik[idx] = a;  // sum over i,k  (j fixed)
    ssjk[idx] = c;  // sum over j,k  (i fixed; idx>>6 plays role of i)
  }
  __syncthreads();
  if (tid < 64){
    float a = 0.f;
    for (int k = 0; k < 40; ++k) a += ssij[k*64 + tid];
    ss2[tid] = a;
  }
  __syncthreads();
  for (int idx = tid; idx < 1280; idx += 256){
    int k = idx >> 5, o = idx & 31;
    float a4 = 0.f, a5 = 0.f, a6 = 0.f;
    for (int d = 0; d < 64; ++d){
      a4 += ssij[k*64+d] * e2w[4*2048 + d*32 + o];
      a5 += ssik[k*64+d] * e2w[5*2048 + d*32 + o];
      a6 += ssjk[k*64+d] * e2w[6*2048 + d*32 + o];
    }
    A4[(b*40+k)*32 + o] = a4;
    A5[(b*40+k)*32 + o] = a5;
    A6[(b*40+k)*32 + o] = a6;
  }
  if (tid < 32){
    float a = e2b[tid];
    for (int d = 0; d < 64; ++d) a += ss2[d] * e2w[7*2048 + d*32 + tid];
    A7[b*32 + tid] = a;
  }
}

// ---------------- big addend tensors: A1p=si2@W'1+A4, A2t=sj2@W'2, Cc=sk2@W'3+A5+A6+A7 ----------------
__global__ __launch_bounds__(256) void k5b(const float* __restrict__ si2, const float* __restrict__ sj2,
    const float* __restrict__ sk2, const float* __restrict__ e2w,
    const float* __restrict__ A4, const float* __restrict__ A5, const float* __restrict__ A6,
    const float* __restrict__ A7,
    float* __restrict__ A1p, float* __restrict__ A2t, float* __restrict__ Cc){
  int which = blockIdx.y;
  int blk = blockIdx.x, b = blk/40, f = blk%40, tid = threadIdx.x;
  __shared__ float src[2560];
  __shared__ float wt[32*65];
  const float* S = (which == 0) ? si2 : (which == 1) ? sj2 : sk2;
  int wop = which + 1;
  for (int idx = tid; idx < 2560; idx += 256) src[idx] = S[(size_t)(b*40+f)*2560 + idx];
  for (int idx = tid; idx < 2048; idx += 256){
    int o = idx >> 6, d = idx & 63;
    wt[o*65 + d] = e2w[wop*2048 + d*32 + o];
  }
  __syncthreads();
  for (int idx = tid; idx < 1280; idx += 256){
    int r = idx >> 5, o = idx & 31;
    float a = 0.f;
    for (int d = 0; d < 64; ++d) a += src[r*64 + d] * wt[o*65 + d];
    size_t oi = ((size_t)(b*40+f)*40 + r)*32 + o;
    if (which == 0)      A1p[oi] = a + A4[(b*40+r)*32 + o];
    else if (which == 1) A2t[oi] = a;
    else                 Cc[oi]  = a + A5[(b*40+r)*32 + o] + A6[(b*40+f)*32 + o] + A7[b*32 + o];
  }
}

// ---------------- final: sum_j out_part, relu, dot out_w ----------------
__global__ __launch_bounds__(64) void k7(const float* __restrict__ out_part, const float* __restrict__ ow,
                                         const float* __restrict__ ob, float* __restrict__ out){
  int b = threadIdx.x;
  if (b < 16){
    float res = ob[0];
    for (int o = 0; o < 32; ++o){
      float s = 0.f;
      for (int j = 0; j < 40; ++j) s += out_part[(b*40+j)*32 + o];
      s = s > 0.f ? s : 0.f;
      res += s * ow[o];
    }
    out[b] = res;
  }
}

extern "C" void kernel_launch(void* const* d_in, const int* in_sizes, int n_in,
                              void* d_out, int out_size, void* d_ws, size_t ws_size,
                              hipStream_t stream){
  const float* x    = (const float*)d_in[0];
  const float* c1w  = (const float*)d_in[1];
  const float* c1b  = (const float*)d_in[2];
  const float* c2w  = (const float*)d_in[3];
  const float* c2b  = (const float*)d_in[4];
  const float* fcw  = (const float*)d_in[5];
  const float* fcb  = (const float*)d_in[6];
  const float* e1w  = (const float*)d_in[7];
  const float* e1b  = (const float*)d_in[8];
  const float* e2w  = (const float*)d_in[9];
  const float* e2b  = (const float*)d_in[10];
  const float* ow   = (const float*)d_in[11];
  const float* ob   = (const float*)d_in[12];

  char* ws = (char*)d_ws;
  size_t off = 0;
  auto alloc = [&](size_t bytes) -> void* {
    void* p = ws + off;
    off += (bytes + 255) & ~(size_t)255;
    return p;
  };
  float* z1   = (float*)alloc((size_t)640*4608*4);
  float* e_f  = (float*)alloc(40960*4);
  u16*   e_b  = (u16*)  alloc(40960*2);
  float* Sg   = (float*)alloc(1024*4);
  u16*   Vt   = (u16*)  alloc((size_t)16*16384*2);
  float* c0   = (float*)alloc(1024*4);
  float* P5   = (float*)alloc(40960*4);
  float* P6   = (float*)alloc(40960*4);
  u16*   W2T0 = (u16*)  alloc(2048*2);
  float* Q3   = (float*)alloc((size_t)1638400*4);
  float* si2  = (float*)alloc((size_t)1638400*4);
  float* sj2  = (float*)alloc((size_t)1638400*4);
  float* sk2  = (float*)alloc((size_t)1638400*4);
  float* A4   = (float*)alloc(20480*4);
  float* A5   = (float*)alloc(20480*4);
  float* A6   = (float*)alloc(20480*4);
  float* A7   = (float*)alloc(512*4);
  float* A1p  = (float*)alloc((size_t)819200*4);
  float* A2t  = (float*)alloc((size_t)819200*4);
  float* Cc   = (float*)alloc((size_t)819200*4);
  float* op   = (float*)alloc(20480*4);
  (void)in_sizes; (void)n_in; (void)out_size; (void)ws_size;

  kconv1<<<640, 256, 0, stream>>>(x, c1w, c1b, z1);
  kconv2<<<640, 256, 0, stream>>>(z1, c2w, c2b, fcw, fcb, e_f, e_b);
  kprep <<<16,  256, 0, stream>>>(e_f, e1w, e1b, e2w, Sg, Vt, c0, P5, P6, W2T0);
  kq3   <<<640, 256, 0, stream>>>(e_f, Sg, e1w, Q3);
  kh    <<<640, 256, 0, stream>>>(0, e_b, Vt, Q3, P5, P6, c0, si2, sk2, W2T0, A1p, A2t, Cc, op);
  kh    <<<640, 256, 0, stream>>>(1, e_b, Vt, Q3, P5, P6, c0, sj2, sk2, W2T0, A1p, A2t, Cc, op);
  k5a   <<<16,  256, 0, stream>>>(si2, sj2, e2w, e2b, A4, A5, A6, A7);
  k5b   <<<dim3(640,3), 256, 0, stream>>>(si2, sj2, sk2, e2w, A4, A5, A6, A7, A1p, A2t, Cc);
  kh    <<<640, 256, 0, stream>>>(2, e_b, Vt, Q3, P5, P6, c0, si2, sk2, W2T0, A1p, A2t, Cc, op);
  k7    <<<1, 64, 0, stream>>>(op, ow, ob, (float*)d_out);
}

// Round 2
// 569.478 us; speedup vs baseline: 1.7691x; 1.7691x over previous
//
#include <hip/hip_runtime.h>
#include <hip/hip_bf16.h>

// UniqueEq3Net: conv stack -> e(640,64); t = e⊗e⊗e never materialized.
// Layer1: h[b,i,j,k,o] = relu( (U⊙e_i)·B1 + U·B0 + Q3c[i,j,o] )   (mode0: fix j)
//   mode0: B1 = diag(e_j)W0 + diag(S)W2 ; B0 = diag(e_j⊙S)W1 + diag(S²)W4
//   mode1: B1 = diag(e_i)W0 + diag(S)W1 ; B0 = diag(e_i⊙S)W2 + diag(S²)W4
// B1/B0 fixed per block -> fragments in registers; Y0=U·B0 once -> acc init.
// Loop body: no barriers (modes 0/1), si2/sj2 accumulate in registers.

typedef unsigned short u16;
typedef __attribute__((ext_vector_type(8))) short bf8_t;   // 8 bf16 (4 VGPRs)
typedef __attribute__((ext_vector_type(4))) float f4_t;

#define LSTR 72   // padded LDS row stride (u16): 144B rows, 16B-aligned

__device__ inline u16 f2bf(float f){
  union { float f; unsigned u; } v; v.f = f;
  unsigned r = v.u + 0x7fffu + ((v.u >> 16) & 1u);
  return (u16)(r >> 16);
}
__device__ inline float bflo(unsigned u){ union { unsigned x; float f; } v; v.x = u << 16; return v.f; }
__device__ inline float bfhi(unsigned u){ union { unsigned x; float f; } v; v.x = u & 0xffff0000u; return v.f; }
__device__ inline unsigned pack2(float a, float b){ return (unsigned)f2bf(a) | ((unsigned)f2bf(b) << 16); }
// truncating pack (round-toward-zero) -- 2 ops, used in the hot loop
__device__ inline unsigned pack2t(float a, float b){
  union { float f; unsigned u; } x, y; x.f = a; y.f = b;
  return (x.u >> 16) | (y.u & 0xffff0000u);
}
__device__ inline void unpack8(bf8_t x, float* o){
  union { bf8_t v; unsigned u[4]; } q; q.v = x;
  #pragma unroll
  for (int p = 0; p < 4; ++p){ o[2*p] = bflo(q.u[p]); o[2*p+1] = bfhi(q.u[p]); }
}
__device__ inline bf8_t mul_frag(const float* uf, const float* ef){
  union { bf8_t v; unsigned u[4]; } r;
  #pragma unroll
  for (int p = 0; p < 4; ++p)
    r.u[p] = pack2t(uf[2*p]*ef[2*p], uf[2*p+1]*ef[2*p+1]);
  return r.v;
}

// ---------------- conv1 + pool -> z1 (640,32,12,12) ----------------
__global__ __launch_bounds__(256) void kconv1(const float* __restrict__ x, const float* __restrict__ w1,
                                              const float* __restrict__ b1, float* __restrict__ z1){
  __shared__ float simg[784];
  __shared__ float sw[800];
  __shared__ float sb[32];
  int img = blockIdx.x, tid = threadIdx.x;
  for (int i = tid; i < 784; i += 256) simg[i] = x[img*784 + i];
  for (int i = tid; i < 800; i += 256) sw[i] = w1[i];
  if (tid < 32) sb[tid] = b1[tid];
  __syncthreads();
  for (int idx = tid; idx < 4608; idx += 256){
    int c = idx / 144, p = idx % 144, py = p / 12, px = p % 12;
    const float* wc = &sw[c*25];
    float mx = -1e30f;
    #pragma unroll
    for (int sy = 0; sy < 2; ++sy)
    #pragma unroll
    for (int sx = 0; sx < 2; ++sx){
      int y0 = 2*py + sy, x0 = 2*px + sx;
      float s = sb[c];
      #pragma unroll
      for (int dy = 0; dy < 5; ++dy)
      #pragma unroll
      for (int dx = 0; dx < 5; ++dx)
        s += simg[(y0+dy)*28 + x0+dx] * wc[dy*5+dx];
      mx = fmaxf(mx, s);
    }
    z1[(size_t)img*4608 + idx] = fmaxf(mx, 0.f);
  }
}

// ---------------- conv2 + pool + fc -> e (640,64) fp32 + bf16 ----------------
__global__ __launch_bounds__(256) void kconv2(const float* __restrict__ z1, const float* __restrict__ w2,
                                              const float* __restrict__ b2, const float* __restrict__ fcw,
                                              const float* __restrict__ fcb,
                                              float* __restrict__ e_f, u16* __restrict__ e_b){
  __shared__ float sz1[4608];
  __shared__ float swc[6400];   // 8 out-channels x 32 x 25
  __shared__ float sz2[1024];
  __shared__ float spart[1024]; // [pos][tid]
  int img = blockIdx.x, tid = threadIdx.x;
  for (int i = tid; i < 4608; i += 256) sz1[i] = z1[(size_t)img*4608 + i];
  int half = tid >> 7, rem = tid & 127;
  int c2l = rem >> 4, p = rem & 15, py = p >> 2, px = p & 3;
  int ybase = 2*py, xbase = 2*px;
  for (int ch = 0; ch < 8; ++ch){
    __syncthreads();
    for (int i = tid; i < 6400; i += 256) swc[i] = w2[ch*6400 + i];
    __syncthreads();
    float s0=0.f, s1=0.f, s2=0.f, s3=0.f;
    for (int c = half*16; c < half*16 + 16; ++c){
      float patch[36];
      const float* zz = &sz1[c*144 + ybase*12 + xbase];
      #pragma unroll
      for (int yy = 0; yy < 6; ++yy)
      #pragma unroll
      for (int xx = 0; xx < 6; ++xx) patch[yy*6+xx] = zz[yy*12+xx];
      const float* ww = &swc[c2l*800 + c*25];
      #pragma unroll
      for (int dy = 0; dy < 5; ++dy)
      #pragma unroll
      for (int dx = 0; dx < 5; ++dx){
        float w = ww[dy*5+dx];
        s0 += patch[dy*6+dx]   * w;
        s1 += patch[dy*6+dx+1] * w;
        s2 += patch[(dy+1)*6+dx]   * w;
        s3 += patch[(dy+1)*6+dx+1] * w;
      }
    }
    spart[0*256 + tid] = s0; spart[1*256 + tid] = s1;
    spart[2*256 + tid] = s2; spart[3*256 + tid] = s3;
    __syncthreads();
    if (tid < 128){
      int c2 = ch*8 + (tid >> 4);
      float v0 = spart[0*256 + tid] + spart[0*256 + 128 + tid];
      float v1 = spart[1*256 + tid] + spart[1*256 + 128 + tid];
      float v2 = spart[2*256 + tid] + spart[2*256 + 128 + tid];
      float v3 = spart[3*256 + tid] + spart[3*256 + 128 + tid];
      float mx = fmaxf(fmaxf(v0, v1), fmaxf(v2, v3)) + b2[c2];
      sz2[c2*16 + (tid & 15)] = fmaxf(mx, 0.f);
    }
  }
  __syncthreads();
  if (tid < 64){
    float a = fcb[tid];
    for (int f = 0; f < 1024; ++f) a += sz2[f] * fcw[f*64 + tid];
    a = fmaxf(a, 0.f);
    e_f[img*64 + tid] = a;
    e_b[img*64 + tid] = f2bf(a);
  }
}

// ---------------- per-b precompute: S, Vt(bf16 x4), c0, P5, P6, W2T0 ----------------
__global__ __launch_bounds__(256) void kprep(const float* __restrict__ e_f, const float* __restrict__ e1w,
    const float* __restrict__ e1b, const float* __restrict__ e2w,
    float* __restrict__ Sg, u16* __restrict__ Vt, float* __restrict__ c0,
    float* __restrict__ P5, float* __restrict__ P6, u16* __restrict__ W2T0){
  int b = blockIdx.x, tid = threadIdx.x;
  __shared__ float se[2560];
  __shared__ float S[64], S2[64], S3[64];
  for (int i = tid; i < 2560; i += 256) se[i] = e_f[b*2560 + i];
  __syncthreads();
  if (tid < 64){
    float s = 0.f;
    for (int i = 0; i < 40; ++i) s += se[i*64 + tid];
    S[tid] = s; S2[tid] = s*s; S3[tid] = s*s*s; Sg[b*64 + tid] = s;
  }
  __syncthreads();
  // Vt layout [b][m][o][d] bf16; m: 0=W0^T 1=(S⊙W1)^T 2=(S⊙W2)^T 3=(S²⊙W4)^T
  for (int idx = tid; idx < 16384; idx += 256){
    int m = idx >> 12, rc = idx & 4095, o = rc >> 6, d = rc & 63;
    float v;
    if (m == 0)      v = e1w[d*64 + o];
    else if (m == 1) v = S[d] * e1w[4096  + d*64 + o];
    else if (m == 2) v = S[d] * e1w[8192  + d*64 + o];
    else             v = S2[d] * e1w[16384 + d*64 + o];
    Vt[(size_t)b*16384 + idx] = f2bf(v);
  }
  if (tid < 64){
    float a = e1b[tid];
    for (int d = 0; d < 64; ++d) a += S3[d] * e1w[7*4096 + d*64 + tid];
    c0[b*64 + tid] = a;
  }
  for (int idx = tid; idx < 2560; idx += 256){
    int j = idx >> 6, o = idx & 63;
    float a5 = 0.f, a6 = 0.f;
    for (int d = 0; d < 64; ++d){
      float es = se[j*64 + d] * S2[d];
      a5 += es * e1w[5*4096 + d*64 + o];
      a6 += es * e1w[6*4096 + d*64 + o];
    }
    P5[(b*40+j)*64 + o] = a5;
    P6[(b*40+j)*64 + o] = a6;
  }
  if (b == 0){
    for (int idx = tid; idx < 2048; idx += 256){
      int o = idx >> 6, d = idx & 63;
      W2T0[o*64 + d] = f2bf(e2w[d*32 + o]);   // W'0 transposed, bf16
    }
  }
}

// ---------------- Q3c[b,i,j,o] = sum_d (e_i e_j S)[d] W3[d,o] + P5[j,o]+P6[i,o]+c0[b,o] ----------------
__global__ __launch_bounds__(256) void kq3(const float* __restrict__ e_f, const float* __restrict__ Sg,
    const float* __restrict__ e1w, const float* __restrict__ P5, const float* __restrict__ P6,
    const float* __restrict__ c0, float* __restrict__ Q3c){
  int blk = blockIdx.x, b = blk/40, i = blk%40, tid = threadIdx.x;
  __shared__ float w3[4096];
  __shared__ float se[2560];
  __shared__ float t3[64];
  for (int idx = tid; idx < 4096; idx += 256) w3[idx] = e1w[12288 + idx];
  for (int idx = tid; idx < 2560; idx += 256) se[idx] = e_f[b*2560 + idx];
  __syncthreads();
  if (tid < 64) t3[tid] = se[i*64 + tid] * Sg[b*64 + tid];
  __syncthreads();
  for (int idx = tid; idx < 2560; idx += 256){
    int j = idx >> 6, o = idx & 63;
    float a = 0.f;
    for (int d = 0; d < 64; ++d) a += t3[d] * se[j*64 + d] * w3[d*64 + o];
    Q3c[((size_t)(b*40+i)*40 + j)*64 + o] =
        a + P5[(b*40+j)*64 + o] + P6[(b*40+i)*64 + o] + c0[b*64 + o];
  }
}

// ---------------- layer-1 reduction passes (modes 0 & 1 fused), barrier-free loop ----------------
__global__ __launch_bounds__(256, 2) void kh01(
    const u16* __restrict__ e_b, const u16* __restrict__ Vt, const float* __restrict__ Q3c,
    float* __restrict__ si2, float* __restrict__ sj2, float* __restrict__ sk2)
{
  __shared__ __align__(16) u16 sU[48*LSTR];
  __shared__ __align__(16) u16 sB1[64*LSTR];
  __shared__ __align__(16) u16 sB0[64*LSTR];
  const int tid = threadIdx.x;
  const int b = blockIdx.x / 40, fix = blockIdx.x % 40;
  const int mode = blockIdx.y;                 // 0: fix=j loop i -> si2,sk2 ; 1: fix=i loop j -> sj2
  const int wave = tid >> 6, lane = tid & 63, l15 = lane & 15, quad = lane >> 4;

  for (int idx = tid; idx < 1536; idx += 256){
    int r = idx >> 5, c = idx & 31;
    unsigned v = (r < 40) ? ((const unsigned*)e_b)[(b*40 + r)*32 + c] : 0u;
    ((unsigned*)(sU + r*LSTR))[c] = v;
  }
  const unsigned* eg = (const unsigned*)(e_b + (size_t)(b*40 + fix)*64);
  const unsigned* Vb = (const unsigned*)(Vt + (size_t)b*16384);
  for (int idx = tid; idx < 2048; idx += 256){
    int o = idx >> 5, d2 = idx & 31;
    unsigned eu = eg[d2];
    unsigned v0 = Vb[o*32 + d2];
    unsigned vA = Vb[(2-mode)*2048 + o*32 + d2];
    unsigned vB = Vb[(1+mode)*2048 + o*32 + d2];
    unsigned v3 = Vb[3*2048 + o*32 + d2];
    float e0 = bflo(eu), e1 = bfhi(eu);
    ((unsigned*)(sB1 + o*LSTR))[d2] = pack2(e0*bflo(v0)+bflo(vA), e1*bfhi(v0)+bfhi(vA));
    ((unsigned*)(sB0 + o*LSTR))[d2] = pack2(e0*bflo(vB)+bflo(v3), e1*bfhi(vB)+bfhi(v3));
  }
  __syncthreads();

  float uf[3][2][8];
  f4_t Y0[3];
  bf8_t b1f[2];
  {
    bf8_t b0f[2];
    #pragma unroll
    for (int ks = 0; ks < 2; ++ks){
      b1f[ks] = *(const bf8_t*)&sB1[(wave*16 + l15)*LSTR + ks*32 + quad*8];
      b0f[ks] = *(const bf8_t*)&sB0[(wave*16 + l15)*LSTR + ks*32 + quad*8];
    }
    #pragma unroll
    for (int m = 0; m < 3; ++m){
      f4_t a = (f4_t){0.f,0.f,0.f,0.f};
      #pragma unroll
      for (int ks = 0; ks < 2; ++ks){
        bf8_t ua = *(const bf8_t*)&sU[(m*16 + l15)*LSTR + ks*32 + quad*8];
        unpack8(ua, uf[m][ks]);
        a = __builtin_amdgcn_mfma_f32_16x16x32_bf16(ua, b0f[ks], a, 0, 0, 0);
      }
      Y0[m] = a;
    }
  }

  const int o1 = wave*16 + l15;
  float sacc[3][4] = {};
  for (int l = 0; l < 40; ++l){
    const int qidx = mode ? (fix*40 + l) : (l*40 + fix);
    float cadd = Q3c[((size_t)(b*1600 + qidx))*64 + o1];
    float ef[2][8];
    #pragma unroll
    for (int ks = 0; ks < 2; ++ks){
      bf8_t ev = *(const bf8_t*)&sU[l*LSTR + ks*32 + quad*8];
      unpack8(ev, ef[ks]);
    }
    f4_t acc[3];
    #pragma unroll
    for (int m = 0; m < 3; ++m){
      f4_t a = Y0[m];
      a = __builtin_amdgcn_mfma_f32_16x16x32_bf16(mul_frag(uf[m][0], ef[0]), b1f[0], a, 0, 0, 0);
      a = __builtin_amdgcn_mfma_f32_16x16x32_bf16(mul_frag(uf[m][1], ef[1]), b1f[1], a, 0, 0, 0);
      acc[m] = a;
    }
    float hs = 0.f;
    #pragma unroll
    for (int m = 0; m < 3; ++m)
      #pragma unroll
      for (int r = 0; r < 4; ++r){
        int kk = m*16 + quad*4 + r;
        float h = fmaxf(acc[m][r] + cadd, 0.f);
        h = (kk < 40) ? h : 0.f;
        sacc[m][r] += h; hs += h;
      }
    if (mode == 0){
      hs += __shfl_xor(hs, 16);
      hs += __shfl_xor(hs, 32);
      if (lane < 16) sk2[((size_t)((b*40 + l)*40 + fix))*64 + o1] = hs;
    }
  }
  float* dst = mode ? sj2 : si2;
  #pragma unroll
  for (int m = 0; m < 3; ++m)
    #pragma unroll
    for (int r = 0; r < 4; ++r){
      int kk = m*16 + quad*4 + r;
      if (kk < 40) dst[((size_t)((b*40 + fix)*40 + kk))*64 + o1] = sacc[m][r];
    }
}

// ---------------- pair sums + small addends ----------------
__global__ __launch_bounds__(256) void k5a(const float* __restrict__ si2, const float* __restrict__ sj2,
    const float* __restrict__ e2w, const float* __restrict__ e2b,
    float* __restrict__ A4, float* __restrict__ A5, float* __restrict__ A6, float* __restrict__ A7){
  int b = blockIdx.x, tid = threadIdx.x;
  __shared__ float ssij[2560], ssik[2560], ssjk[2560], ss2[64];
  for (int idx = tid; idx < 2560; idx += 256){
    int k = idx >> 6, d = idx & 63;
    float a = 0.f;
    for (int j = 0; j < 40; ++j) a += si2[((size_t)(b*40+j)*40 + k)*64 + d];
    ssij[idx] = a;
  }
  for (int idx = tid; idx < 2560; idx += 256){
    int j = idx >> 6, d = idx & 63;
    float a = 0.f, c = 0.f;
    const float* p = &si2[(size_t)(b*40+j)*2560 + d];
    const float* q = &sj2[(size_t)(b*40+j)*2560 + d];
    for (int k = 0; k < 40; ++k){ a += p[k*64]; c += q[k*64]; }
    ssik[idx] = a;
    ssjk[idx] = c;
  }
  __syncthreads();
  if (tid < 64){
    float a = 0.f;
    for (int k = 0; k < 40; ++k) a += ssij[k*64 + tid];
    ss2[tid] = a;
  }
  __syncthreads();
  for (int idx = tid; idx < 1280; idx += 256){
    int k = idx >> 5, o = idx & 31;
    float a4 = 0.f, a5 = 0.f, a6 = 0.f;
    for (int d = 0; d < 64; ++d){
      a4 += ssij[k*64+d] * e2w[4*2048 + d*32 + o];
      a5 += ssik[k*64+d] * e2w[5*2048 + d*32 + o];
      a6 += ssjk[k*64+d] * e2w[6*2048 + d*32 + o];
    }
    A4[(b*40+k)*32 + o] = a4;
    A5[(b*40+k)*32 + o] = a5;
    A6[(b*40+k)*32 + o] = a6;
  }
  if (tid < 32){
    float a = e2b[tid];
    for (int d = 0; d < 64; ++d) a += ss2[d] * e2w[7*2048 + d*32 + tid];
    A7[b*32 + tid] = a;
  }
}

// ---------------- big addends: A1p=si2@W'1+A4, A2t=sj2@W'2, Cc=sk2@W'3+A5+A6+A7 ----------------
__global__ __launch_bounds__(256) void k5b(const float* __restrict__ si2, const float* __restrict__ sj2,
    const float* __restrict__ sk2, const float* __restrict__ e2w,
    const float* __restrict__ A4, const float* __restrict__ A5, const float* __restrict__ A6,
    const float* __restrict__ A7,
    float* __restrict__ A1p, float* __restrict__ A2t, float* __restrict__ Cc){
  int which = blockIdx.y;
  int blk = blockIdx.x, b = blk/40, f = blk%40, tid = threadIdx.x;
  __shared__ float src[2560];
  __shared__ float wt[32*65];
  const float* S = (which == 0) ? si2 : (which == 1) ? sj2 : sk2;
  int wop = which + 1;
  for (int idx = tid; idx < 2560; idx += 256) src[idx] = S[(size_t)(b*40+f)*2560 + idx];
  for (int idx = tid; idx < 2048; idx += 256){
    int o = idx >> 6, d = idx & 63;
    wt[o*65 + d] = e2w[wop*2048 + d*32 + o];
  }
  __syncthreads();
  for (int idx = tid; idx < 1280; idx += 256){
    int r = idx >> 5, o = idx & 31;
    float a = 0.f;
    for (int d = 0; d < 64; ++d) a += src[r*64 + d] * wt[o*65 + d];
    size_t oi = ((size_t)(b*40+f)*40 + r)*32 + o;
    if (which == 0)      A1p[oi] = a + A4[(b*40+r)*32 + o];
    else if (which == 1) A2t[oi] = a;
    else                 Cc[oi]  = a + A5[(b*40+r)*32 + o] + A6[(b*40+f)*32 + o] + A7[b*32 + o];
  }
}

// ---------------- mode2: layer-2 evaluation; block=(b,j), loop i ----------------
__global__ __launch_bounds__(256, 2) void kh2(
    const u16* __restrict__ e_b, const u16* __restrict__ Vt, const float* __restrict__ Q3c,
    const u16* __restrict__ W2T0,
    const float* __restrict__ A1p, const float* __restrict__ A2t, const float* __restrict__ Cc,
    float* __restrict__ out_part)
{
  __shared__ __align__(16) u16 sU[48*LSTR];
  __shared__ __align__(16) u16 sB1[64*LSTR];
  __shared__ __align__(16) u16 sB0[64*LSTR];
  __shared__ __align__(16) u16 sW2[32*LSTR];
  __shared__ __align__(16) u16 sH[48*LSTR];
  const int tid = threadIdx.x;
  const int b = blockIdx.x / 40, fix = blockIdx.x % 40;   // fix = j
  const int wave = tid >> 6, lane = tid & 63, l15 = lane & 15, quad = lane >> 4;

  for (int idx = tid; idx < 1536; idx += 256){
    int r = idx >> 5, c = idx & 31;
    unsigned v = (r < 40) ? ((const unsigned*)e_b)[(b*40 + r)*32 + c] : 0u;
    ((unsigned*)(sU + r*LSTR))[c] = v;
  }
  const unsigned* eg = (const unsigned*)(e_b + (size_t)(b*40 + fix)*64);
  const unsigned* Vb = (const unsigned*)(Vt + (size_t)b*16384);
  for (int idx = tid; idx < 2048; idx += 256){
    int o = idx >> 5, d2 = idx & 31;
    unsigned eu = eg[d2];
    unsigned v0 = Vb[o*32 + d2];
    unsigned vA = Vb[2*2048 + o*32 + d2];
    unsigned vB = Vb[1*2048 + o*32 + d2];
    unsigned v3 = Vb[3*2048 + o*32 + d2];
    float e0 = bflo(eu), e1 = bfhi(eu);
    ((unsigned*)(sB1 + o*LSTR))[d2] = pack2(e0*bflo(v0)+bflo(vA), e1*bfhi(v0)+bfhi(vA));
    ((unsigned*)(sB0 + o*LSTR))[d2] = pack2(e0*bflo(vB)+bflo(v3), e1*bfhi(vB)+bfhi(v3));
  }
  for (int idx = tid; idx < 1024; idx += 256){
    int o = idx >> 5, c = idx & 31;
    ((unsigned*)(sW2 + o*LSTR))[c] = ((const unsigned*)W2T0)[idx];
  }
  __syncthreads();

  float uf[3][2][8];
  f4_t Y0[3];
  bf8_t b1f[2], wf[2];
  {
    bf8_t b0f[2];
    #pragma unroll
    for (int ks = 0; ks < 2; ++ks){
      b1f[ks] = *(const bf8_t*)&sB1[(wave*16 + l15)*LSTR + ks*32 + quad*8];
      b0f[ks] = *(const bf8_t*)&sB0[(wave*16 + l15)*LSTR + ks*32 + quad*8];
      wf[ks]  = *(const bf8_t*)&sW2[((wave&1)*16 + l15)*LSTR + ks*32 + quad*8];
    }
    #pragma unroll
    for (int m = 0; m < 3; ++m){
      f4_t a = (f4_t){0.f,0.f,0.f,0.f};
      #pragma unroll
      for (int ks = 0; ks < 2; ++ks){
        bf8_t ua = *(const bf8_t*)&sU[(m*16 + l15)*LSTR + ks*32 + quad*8];
        unpack8(ua, uf[m][ks]);
        a = __builtin_amdgcn_mfma_f32_16x16x32_bf16(ua, b0f[ks], a, 0, 0, 0);
      }
      Y0[m] = a;
    }
  }

  const int o1 = wave*16 + l15;
  const int o2 = (wave & 1)*16 + l15;
  float pa1[3][4];
  if (wave < 2){
    #pragma unroll
    for (int m = 0; m < 3; ++m)
      #pragma unroll
      for (int r = 0; r < 4; ++r){
        int kk = m*16 + quad*4 + r;
        pa1[m][r] = (kk < 40) ? A1p[((size_t)((b*40 + fix)*40 + kk))*32 + o2] : 0.f;
      }
  }
  float psum = 0.f;

  for (int l = 0; l < 40; ++l){
    float cadd = Q3c[((size_t)(b*1600 + l*40 + fix))*64 + o1];
    float ccv = 0.f;
    float a2[3][4];
    if (wave < 2){
      ccv = Cc[((size_t)((b*40 + l)*40 + fix))*32 + o2];
      #pragma unroll
      for (int m = 0; m < 3; ++m)
        #pragma unroll
        for (int r = 0; r < 4; ++r){
          int kk = m*16 + quad*4 + r;
          a2[m][r] = (kk < 40) ? A2t[((size_t)((b*40 + l)*40 + kk))*32 + o2] : 0.f;
        }
    }
    float ef[2][8];
    #pragma unroll
    for (int ks = 0; ks < 2; ++ks){
      bf8_t ev = *(const bf8_t*)&sU[l*LSTR + ks*32 + quad*8];
      unpack8(ev, ef[ks]);
    }
    f4_t acc[3];
    #pragma unroll
    for (int m = 0; m < 3; ++m){
      f4_t a = Y0[m];
      a = __builtin_amdgcn_mfma_f32_16x16x32_bf16(mul_frag(uf[m][0], ef[0]), b1f[0], a, 0, 0, 0);
      a = __builtin_amdgcn_mfma_f32_16x16x32_bf16(mul_frag(uf[m][1], ef[1]), b1f[1], a, 0, 0, 0);
      acc[m] = a;
    }
    #pragma unroll
    for (int m = 0; m < 3; ++m)
      #pragma unroll
      for (int r = 0; r < 4; ++r){
        int kk = m*16 + quad*4 + r;
        float h = acc[m][r] + cadd;
        sH[kk*LSTR + o1] = (kk < 40 && h > 0.f) ? f2bf(h) : (u16)0;
      }
    __syncthreads();
    if (wave < 2){
      f4_t y[3];
      y[0] = (f4_t){0.f,0.f,0.f,0.f}; y[1] = y[0]; y[2] = y[0];
      #pragma unroll
      for (int ks = 0; ks < 2; ++ks){
        #pragma unroll
        for (int m = 0; m < 3; ++m){
          bf8_t ha = *(const bf8_t*)&sH[(m*16 + l15)*LSTR + ks*32 + quad*8];
          y[m] = __builtin_amdgcn_mfma_f32_16x16x32_bf16(ha, wf[ks], y[m], 0, 0, 0);
        }
      }
      #pragma unroll
      for (int m = 0; m < 3; ++m)
        #pragma unroll
        for (int r = 0; r < 4; ++r){
          int kk = m*16 + quad*4 + r;
          if (kk < 40){
            float v = y[m][r] + pa1[m][r] + a2[m][r] + ccv;
            psum += v > 0.f ? v : 0.f;
          }
        }
    }
    __syncthreads();
  }
  psum += __shfl_xor(psum, 16);
  psum += __shfl_xor(psum, 32);
  if (wave < 2 && lane < 16)
    out_part[(b*40 + fix)*32 + o2] = psum;
}

// ---------------- final: sum_j out_part, relu, dot out_w ----------------
__global__ __launch_bounds__(64) void k7(const float* __restrict__ out_part, const float* __restrict__ ow,
                                         const float* __restrict__ ob, float* __restrict__ out){
  int b = threadIdx.x;
  if (b < 16){
    float res = ob[0];
    for (int o = 0; o < 32; ++o){
      float s = 0.f;
      for (int j = 0; j < 40; ++j) s += out_part[(b*40+j)*32 + o];
      s = s > 0.f ? s : 0.f;
      res += s * ow[o];
    }
    out[b] = res;
  }
}

extern "C" void kernel_launch(void* const* d_in, const int* in_sizes, int n_in,
                              void* d_out, int out_size, void* d_ws, size_t ws_size,
                              hipStream_t stream){
  const float* x    = (const float*)d_in[0];
  const float* c1w  = (const float*)d_in[1];
  const float* c1b  = (const float*)d_in[2];
  const float* c2w  = (const float*)d_in[3];
  const float* c2b  = (const float*)d_in[4];
  const float* fcw  = (const float*)d_in[5];
  const float* fcb  = (const float*)d_in[6];
  const float* e1w  = (const float*)d_in[7];
  const float* e1b  = (const float*)d_in[8];
  const float* e2w  = (const float*)d_in[9];
  const float* e2b  = (const float*)d_in[10];
  const float* ow   = (const float*)d_in[11];
  const float* ob   = (const float*)d_in[12];

  char* ws = (char*)d_ws;
  size_t off = 0;
  auto alloc = [&](size_t bytes) -> void* {
    void* p = ws + off;
    off += (bytes + 255) & ~(size_t)255;
    return p;
  };
  float* z1   = (float*)alloc((size_t)640*4608*4);
  float* e_f  = (float*)alloc(40960*4);
  u16*   e_b  = (u16*)  alloc(40960*2);
  float* Sg   = (float*)alloc(1024*4);
  u16*   Vt   = (u16*)  alloc((size_t)16*16384*2);
  float* c0   = (float*)alloc(1024*4);
  float* P5   = (float*)alloc(40960*4);
  float* P6   = (float*)alloc(40960*4);
  u16*   W2T0 = (u16*)  alloc(2048*2);
  float* Q3c  = (float*)alloc((size_t)1638400*4);
  float* si2  = (float*)alloc((size_t)1638400*4);
  float* sj2  = (float*)alloc((size_t)1638400*4);
  float* sk2  = (float*)alloc((size_t)1638400*4);
  float* A4   = (float*)alloc(20480*4);
  float* A5   = (float*)alloc(20480*4);
  float* A6   = (float*)alloc(20480*4);
  float* A7   = (float*)alloc(512*4);
  float* A1p  = (float*)alloc((size_t)819200*4);
  float* A2t  = (float*)alloc((size_t)819200*4);
  float* Cc   = (float*)alloc((size_t)819200*4);
  float* op   = (float*)alloc(20480*4);
  (void)in_sizes; (void)n_in; (void)out_size; (void)ws_size;

  kconv1<<<640, 256, 0, stream>>>(x, c1w, c1b, z1);
  kconv2<<<640, 256, 0, stream>>>(z1, c2w, c2b, fcw, fcb, e_f, e_b);
  kprep <<<16,  256, 0, stream>>>(e_f, e1w, e1b, e2w, Sg, Vt, c0, P5, P6, W2T0);
  kq3   <<<640, 256, 0, stream>>>(e_f, Sg, e1w, P5, P6, c0, Q3c);
  kh01  <<<dim3(640,2), 256, 0, stream>>>(e_b, Vt, Q3c, si2, sj2, sk2);
  k5a   <<<16,  256, 0, stream>>>(si2, sj2, e2w, e2b, A4, A5, A6, A7);
  k5b   <<<dim3(640,3), 256, 0, stream>>>(si2, sj2, sk2, e2w, A4, A5, A6, A7, A1p, A2t, Cc);
  kh2   <<<640, 256, 0, stream>>>(e_b, Vt, Q3c, W2T0, A1p, A2t, Cc, op);
  k7    <<<1, 64, 0, stream>>>(op, ow, ob, (float*)d_out);
}

// Round 3
// 413.971 us; speedup vs baseline: 2.4336x; 1.3756x over previous
//
#include <hip/hip_runtime.h>
#include <hip/hip_bf16.h>

// UniqueEq3Net: conv stack -> e(640,64); t = e⊗e⊗e never materialized.
// conv2 = 25 shifted K=32 MFMA GEMMs over channels-last z1t (no im2col).
// fc = one 640x64x1024 bf16 MFMA GEMM.
// Layer1: h[b,i,j,k,o] = relu( (U⊙e_i)·B1 + U·B0 + Q3c[i,j,o] )
// Layer2 via 3 recompute passes (kh01 fused modes, kh2 epilogue).

typedef unsigned short u16;
typedef __attribute__((ext_vector_type(8))) short bf8_t;   // 8 bf16 (4 VGPRs)
typedef __attribute__((ext_vector_type(4))) float f4_t;

#define LSTR 72   // padded LDS row stride (u16): 144B rows, 16B-aligned

__device__ inline u16 f2bf(float f){
  union { float f; unsigned u; } v; v.f = f;
  unsigned r = v.u + 0x7fffu + ((v.u >> 16) & 1u);
  return (u16)(r >> 16);
}
__device__ inline float bflo(unsigned u){ union { unsigned x; float f; } v; v.x = u << 16; return v.f; }
__device__ inline float bfhi(unsigned u){ union { unsigned x; float f; } v; v.x = u & 0xffff0000u; return v.f; }
__device__ inline unsigned pack2(float a, float b){ return (unsigned)f2bf(a) | ((unsigned)f2bf(b) << 16); }
__device__ inline unsigned pack2t(float a, float b){
  union { float f; unsigned u; } x, y; x.f = a; y.f = b;
  return (x.u >> 16) | (y.u & 0xffff0000u);
}
__device__ inline void unpack8(bf8_t x, float* o){
  union { bf8_t v; unsigned u[4]; } q; q.v = x;
  #pragma unroll
  for (int p = 0; p < 4; ++p){ o[2*p] = bflo(q.u[p]); o[2*p+1] = bfhi(q.u[p]); }
}
__device__ inline bf8_t mul_frag(const float* uf, const float* ef){
  union { bf8_t v; unsigned u[4]; } r;
  #pragma unroll
  for (int p = 0; p < 4; ++p)
    r.u[p] = pack2t(uf[2*p]*ef[2*p], uf[2*p+1]*ef[2*p+1]);
  return r.v;
}

// ---------------- weight prep: wt2[tap][co][ci] bf16, fcwT[o][k] bf16 ----------------
__global__ __launch_bounds__(256) void kwp(const float* __restrict__ w2, const float* __restrict__ fcw,
                                           u16* __restrict__ wt2, u16* __restrict__ fcwT){
  int tid = blockIdx.x*256 + threadIdx.x, stride = gridDim.x*256;
  for (int i = tid; i < 51200; i += stride){
    int tap = i >> 11, rc = i & 2047, co = rc >> 5, ci = rc & 31;
    wt2[i] = f2bf(w2[co*800 + ci*25 + tap]);
  }
  for (int i = tid; i < 65536; i += stride){
    int o = i >> 10, k = i & 1023;
    fcwT[i] = f2bf(fcw[k*64 + o]);
  }
}

// ---------------- conv1 + pool -> z1t (640, 144 pos, 32 ci) bf16 channels-last ----------------
__global__ __launch_bounds__(256) void kconv1(const float* __restrict__ x, const float* __restrict__ w1,
                                              const float* __restrict__ b1, u16* __restrict__ z1t){
  __shared__ float simg[784];
  int img = blockIdx.x, tid = threadIdx.x;
  for (int i = tid; i < 784; i += 256) simg[i] = x[img*784 + i];
  const int c = tid & 31;
  float wc[25];
  #pragma unroll
  for (int t = 0; t < 25; ++t) wc[t] = w1[c*25 + t];
  const float bb = b1[c];
  __syncthreads();
  #pragma unroll 2
  for (int it = 0; it < 18; ++it){
    int p = (tid >> 5) + it*8;          // 0..143
    int py = p / 12, px = p % 12;
    float patch[36];
    const float* sp = &simg[2*py*28 + 2*px];
    #pragma unroll
    for (int yy = 0; yy < 6; ++yy)
      #pragma unroll
      for (int xx = 0; xx < 6; ++xx) patch[yy*6+xx] = sp[yy*28+xx];
    float mx = -1e30f;
    #pragma unroll
    for (int sy = 0; sy < 2; ++sy)
    #pragma unroll
    for (int sx = 0; sx < 2; ++sx){
      float s = bb;
      #pragma unroll
      for (int dy = 0; dy < 5; ++dy)
        #pragma unroll
        for (int dx = 0; dx < 5; ++dx)
          s += patch[(sy+dy)*6 + sx+dx] * wc[dy*5+dx];
      mx = fmaxf(mx, s);
    }
    z1t[(size_t)img*4608 + p*32 + c] = f2bf(fmaxf(mx, 0.f));
  }
}

// ---------------- conv2 (MFMA, 25 shifted K=32 GEMMs) + pool -> z2g (640,1024) bf16 ----------------
__global__ __launch_bounds__(256) void kconv2m(const u16* __restrict__ z1t, const u16* __restrict__ wt2,
                                               const float* __restrict__ b2, u16* __restrict__ z2g){
  __shared__ __align__(16) u16 sz[4608];   // [pos 144][ci 32]
  __shared__ __align__(16) u16 sz2[1024];
  int img = blockIdx.x, tid = threadIdx.x;
  for (int i = tid; i < 576; i += 256)
    ((uint4*)sz)[i] = ((const uint4*)(z1t + (size_t)img*4608))[i];
  __syncthreads();
  const int wave = tid >> 6, lane = tid & 63, l15 = lane & 15, quad = lane >> 4;
  const int y = wave*2 + (l15 >> 3), x = l15 & 7;   // output pos = wave*16+l15 on 8x8
  f4_t acc[4];
  acc[0] = (f4_t){0.f,0.f,0.f,0.f}; acc[1] = acc[0]; acc[2] = acc[0]; acc[3] = acc[0];
  #pragma unroll
  for (int dy = 0; dy < 5; ++dy)
    #pragma unroll
    for (int dx = 0; dx < 5; ++dx){
      const int tap = dy*5 + dx;
      bf8_t af = *(const bf8_t*)&sz[((y+dy)*12 + (x+dx))*32 + quad*8];
      const u16* wp = wt2 + tap*2048 + l15*32 + quad*8;
      #pragma unroll
      for (int nt = 0; nt < 4; ++nt){
        bf8_t bf = *(const bf8_t*)(wp + nt*512);
        acc[nt] = __builtin_amdgcn_mfma_f32_16x16x32_bf16(af, bf, acc[nt], 0, 0, 0);
      }
    }
  // bias + 2x2 maxpool + relu -> sz2[co*16 + py*4 + px]
  #pragma unroll
  for (int nt = 0; nt < 4; ++nt){
    int co = nt*16 + l15;
    float v0 = fmaxf(acc[nt][0], acc[nt][1]);   // x-pair 0
    float v1 = fmaxf(acc[nt][2], acc[nt][3]);   // x-pair 1
    v0 = fmaxf(v0, __shfl_xor(v0, 32));         // y-pair (quad q <-> q^2)
    v1 = fmaxf(v1, __shfl_xor(v1, 32));
    if (quad < 2){
      float bb = b2[co];
      sz2[co*16 + wave*4 + quad*2 + 0] = f2bf(fmaxf(v0 + bb, 0.f));
      sz2[co*16 + wave*4 + quad*2 + 1] = f2bf(fmaxf(v1 + bb, 0.f));
    }
  }
  __syncthreads();
  if (tid < 128) ((uint4*)(z2g + (size_t)img*1024))[tid] = ((const uint4*)sz2)[tid];
}

// ---------------- fc: e = relu(z2g @ fcw + fcb)  (MFMA, M=640,K=1024,N=64) ----------------
__global__ __launch_bounds__(256) void kfc(const u16* __restrict__ z2g, const u16* __restrict__ fcwT,
                                           const float* __restrict__ fcb,
                                           float* __restrict__ e_f, u16* __restrict__ e_b){
  __shared__ __align__(16) u16 sA[16*1032];
  int img0 = blockIdx.x*16, tid = threadIdx.x;
  for (int i = tid; i < 2048; i += 256){
    int row = i >> 7, c16 = i & 127;
    ((uint4*)(sA + row*1032))[c16] = ((const uint4*)(z2g + (size_t)(img0+row)*1024))[c16];
  }
  __syncthreads();
  const int wave = tid >> 6, lane = tid & 63, l15 = lane & 15, quad = lane >> 4;
  const int o = wave*16 + l15;
  f4_t acc = (f4_t){0.f,0.f,0.f,0.f};
  #pragma unroll 8
  for (int ks = 0; ks < 32; ++ks){
    bf8_t af = *(const bf8_t*)&sA[l15*1032 + ks*32 + quad*8];
    bf8_t bf = *(const bf8_t*)(fcwT + (size_t)o*1024 + ks*32 + quad*8);
    acc = __builtin_amdgcn_mfma_f32_16x16x32_bf16(af, bf, acc, 0, 0, 0);
  }
  const float bb = fcb[o];
  #pragma unroll
  for (int r = 0; r < 4; ++r){
    int img = img0 + quad*4 + r;
    float v = fmaxf(acc[r] + bb, 0.f);
    e_f[img*64 + o] = v;
    e_b[img*64 + o] = f2bf(v);
  }
}

// ---------------- per-b precompute: S, Vt(bf16 x4), c0, P5, P6, W2T0 ----------------
__global__ __launch_bounds__(256) void kprep(const float* __restrict__ e_f, const float* __restrict__ e1w,
    const float* __restrict__ e1b, const float* __restrict__ e2w,
    float* __restrict__ Sg, u16* __restrict__ Vt, float* __restrict__ c0,
    float* __restrict__ P5, float* __restrict__ P6, u16* __restrict__ W2T0){
  int b = blockIdx.x, tid = threadIdx.x;
  __shared__ float se[2560];
  __shared__ float S[64], S2[64], S3[64];
  for (int i = tid; i < 2560; i += 256) se[i] = e_f[b*2560 + i];
  __syncthreads();
  if (tid < 64){
    float s = 0.f;
    for (int i = 0; i < 40; ++i) s += se[i*64 + tid];
    S[tid] = s; S2[tid] = s*s; S3[tid] = s*s*s; Sg[b*64 + tid] = s;
  }
  __syncthreads();
  for (int idx = tid; idx < 16384; idx += 256){
    int m = idx >> 12, rc = idx & 4095, o = rc >> 6, d = rc & 63;
    float v;
    if (m == 0)      v = e1w[d*64 + o];
    else if (m == 1) v = S[d] * e1w[4096  + d*64 + o];
    else if (m == 2) v = S[d] * e1w[8192  + d*64 + o];
    else             v = S2[d] * e1w[16384 + d*64 + o];
    Vt[(size_t)b*16384 + idx] = f2bf(v);
  }
  if (tid < 64){
    float a = e1b[tid];
    for (int d = 0; d < 64; ++d) a += S3[d] * e1w[7*4096 + d*64 + tid];
    c0[b*64 + tid] = a;
  }
  for (int idx = tid; idx < 2560; idx += 256){
    int j = idx >> 6, o = idx & 63;
    float a5 = 0.f, a6 = 0.f;
    for (int d = 0; d < 64; ++d){
      float es = se[j*64 + d] * S2[d];
      a5 += es * e1w[5*4096 + d*64 + o];
      a6 += es * e1w[6*4096 + d*64 + o];
    }
    P5[(b*40+j)*64 + o] = a5;
    P6[(b*40+j)*64 + o] = a6;
  }
  if (b == 0){
    for (int idx = tid; idx < 2048; idx += 256){
      int o = idx >> 6, d = idx & 63;
      W2T0[o*64 + d] = f2bf(e2w[d*32 + o]);
    }
  }
}

// ---------------- Q3c[b,i,j,o] ----------------
__global__ __launch_bounds__(256) void kq3(const float* __restrict__ e_f, const float* __restrict__ Sg,
    const float* __restrict__ e1w, const float* __restrict__ P5, const float* __restrict__ P6,
    const float* __restrict__ c0, float* __restrict__ Q3c){
  int blk = blockIdx.x, b = blk/40, i = blk%40, tid = threadIdx.x;
  __shared__ float w3[4096];
  __shared__ float se[2560];
  __shared__ float t3[64];
  for (int idx = tid; idx < 4096; idx += 256) w3[idx] = e1w[12288 + idx];
  for (int idx = tid; idx < 2560; idx += 256) se[idx] = e_f[b*2560 + idx];
  __syncthreads();
  if (tid < 64) t3[tid] = se[i*64 + tid] * Sg[b*64 + tid];
  __syncthreads();
  for (int idx = tid; idx < 2560; idx += 256){
    int j = idx >> 6, o = idx & 63;
    float a = 0.f;
    for (int d = 0; d < 64; ++d) a += t3[d] * se[j*64 + d] * w3[d*64 + o];
    Q3c[((size_t)(b*40+i)*40 + j)*64 + o] =
        a + P5[(b*40+j)*64 + o] + P6[(b*40+i)*64 + o] + c0[b*64 + o];
  }
}

// ---------------- layer-1 reduction passes (modes 0 & 1 fused), barrier-free loop ----------------
__global__ __launch_bounds__(256, 2) void kh01(
    const u16* __restrict__ e_b, const u16* __restrict__ Vt, const float* __restrict__ Q3c,
    float* __restrict__ si2, float* __restrict__ sj2, float* __restrict__ sk2)
{
  __shared__ __align__(16) u16 sU[48*LSTR];
  __shared__ __align__(16) u16 sB1[64*LSTR];
  __shared__ __align__(16) u16 sB0[64*LSTR];
  const int tid = threadIdx.x;
  const int b = blockIdx.x / 40, fix = blockIdx.x % 40;
  const int mode = blockIdx.y;
  const int wave = tid >> 6, lane = tid & 63, l15 = lane & 15, quad = lane >> 4;

  for (int idx = tid; idx < 1536; idx += 256){
    int r = idx >> 5, c = idx & 31;
    unsigned v = (r < 40) ? ((const unsigned*)e_b)[(b*40 + r)*32 + c] : 0u;
    ((unsigned*)(sU + r*LSTR))[c] = v;
  }
  const unsigned* eg = (const unsigned*)(e_b + (size_t)(b*40 + fix)*64);
  const unsigned* Vb = (const unsigned*)(Vt + (size_t)b*16384);
  for (int idx = tid; idx < 2048; idx += 256){
    int o = idx >> 5, d2 = idx & 31;
    unsigned eu = eg[d2];
    unsigned v0 = Vb[o*32 + d2];
    unsigned vA = Vb[(2-mode)*2048 + o*32 + d2];
    unsigned vB = Vb[(1+mode)*2048 + o*32 + d2];
    unsigned v3 = Vb[3*2048 + o*32 + d2];
    float e0 = bflo(eu), e1 = bfhi(eu);
    ((unsigned*)(sB1 + o*LSTR))[d2] = pack2(e0*bflo(v0)+bflo(vA), e1*bfhi(v0)+bfhi(vA));
    ((unsigned*)(sB0 + o*LSTR))[d2] = pack2(e0*bflo(vB)+bflo(v3), e1*bfhi(vB)+bfhi(v3));
  }
  __syncthreads();

  float uf[3][2][8];
  f4_t Y0[3];
  bf8_t b1f[2];
  {
    bf8_t b0f[2];
    #pragma unroll
    for (int ks = 0; ks < 2; ++ks){
      b1f[ks] = *(const bf8_t*)&sB1[(wave*16 + l15)*LSTR + ks*32 + quad*8];
      b0f[ks] = *(const bf8_t*)&sB0[(wave*16 + l15)*LSTR + ks*32 + quad*8];
    }
    #pragma unroll
    for (int m = 0; m < 3; ++m){
      f4_t a = (f4_t){0.f,0.f,0.f,0.f};
      #pragma unroll
      for (int ks = 0; ks < 2; ++ks){
        bf8_t ua = *(const bf8_t*)&sU[(m*16 + l15)*LSTR + ks*32 + quad*8];
        unpack8(ua, uf[m][ks]);
        a = __builtin_amdgcn_mfma_f32_16x16x32_bf16(ua, b0f[ks], a, 0, 0, 0);
      }
      Y0[m] = a;
    }
  }

  const int o1 = wave*16 + l15;
  float sacc[3][4] = {};
  for (int l = 0; l < 40; ++l){
    const int qidx = mode ? (fix*40 + l) : (l*40 + fix);
    float cadd = Q3c[((size_t)(b*1600 + qidx))*64 + o1];
    float ef[2][8];
    #pragma unroll
    for (int ks = 0; ks < 2; ++ks){
      bf8_t ev = *(const bf8_t*)&sU[l*LSTR + ks*32 + quad*8];
      unpack8(ev, ef[ks]);
    }
    f4_t acc[3];
    #pragma unroll
    for (int m = 0; m < 3; ++m){
      f4_t a = Y0[m];
      a = __builtin_amdgcn_mfma_f32_16x16x32_bf16(mul_frag(uf[m][0], ef[0]), b1f[0], a, 0, 0, 0);
      a = __builtin_amdgcn_mfma_f32_16x16x32_bf16(mul_frag(uf[m][1], ef[1]), b1f[1], a, 0, 0, 0);
      acc[m] = a;
    }
    float hs = 0.f;
    #pragma unroll
    for (int m = 0; m < 3; ++m)
      #pragma unroll
      for (int r = 0; r < 4; ++r){
        int kk = m*16 + quad*4 + r;
        float h = fmaxf(acc[m][r] + cadd, 0.f);
        h = (kk < 40) ? h : 0.f;
        sacc[m][r] += h; hs += h;
      }
    if (mode == 0){
      hs += __shfl_xor(hs, 16);
      hs += __shfl_xor(hs, 32);
      if (lane < 16) sk2[((size_t)((b*40 + l)*40 + fix))*64 + o1] = hs;
    }
  }
  float* dst = mode ? sj2 : si2;
  #pragma unroll
  for (int m = 0; m < 3; ++m)
    #pragma unroll
    for (int r = 0; r < 4; ++r){
      int kk = m*16 + quad*4 + r;
      if (kk < 40) dst[((size_t)((b*40 + fix)*40 + kk))*64 + o1] = sacc[m][r];
    }
}

// ---------------- pair sums + small addends ----------------
__global__ __launch_bounds__(256) void k5a(const float* __restrict__ si2, const float* __restrict__ sj2,
    const float* __restrict__ e2w, const float* __restrict__ e2b,
    float* __restrict__ A4, float* __restrict__ A5, float* __restrict__ A6, float* __restrict__ A7){
  int b = blockIdx.x, tid = threadIdx.x;
  __shared__ float ssij[2560], ssik[2560], ssjk[2560], ss2[64];
  for (int idx = tid; idx < 2560; idx += 256){
    int k = idx >> 6, d = idx & 63;
    float a = 0.f;
    for (int j = 0; j < 40; ++j) a += si2[((size_t)(b*40+j)*40 + k)*64 + d];
    ssij[idx] = a;
  }
  for (int idx = tid; idx < 2560; idx += 256){
    int j = idx >> 6, d = idx & 63;
    float a = 0.f, c = 0.f;
    const float* p = &si2[(size_t)(b*40+j)*2560 + d];
    const float* q = &sj2[(size_t)(b*40+j)*2560 + d];
    for (int k = 0; k < 40; ++k){ a += p[k*64]; c += q[k*64]; }
    ssik[idx] = a;
    ssjk[idx] = c;
  }
  __syncthreads();
  if (tid < 64){
    float a = 0.f;
    for (int k = 0; k < 40; ++k) a += ssij[k*64 + tid];
    ss2[tid] = a;
  }
  __syncthreads();
  for (int idx = tid; idx < 1280; idx += 256){
    int k = idx >> 5, o = idx & 31;
    float a4 = 0.f, a5 = 0.f, a6 = 0.f;
    for (int d = 0; d < 64; ++d){
      a4 += ssij[k*64+d] * e2w[4*2048 + d*32 + o];
      a5 += ssik[k*64+d] * e2w[5*2048 + d*32 + o];
      a6 += ssjk[k*64+d] * e2w[6*2048 + d*32 + o];
    }
    A4[(b*40+k)*32 + o] = a4;
    A5[(b*40+k)*32 + o] = a5;
    A6[(b*40+k)*32 + o] = a6;
  }
  if (tid < 32){
    float a = e2b[tid];
    for (int d = 0; d < 64; ++d) a += ss2[d] * e2w[7*2048 + d*32 + tid];
    A7[b*32 + tid] = a;
  }
}

// ---------------- big addends: A1p=si2@W'1+A4, A2t=sj2@W'2, Cc=sk2@W'3+A5+A6+A7 ----------------
__global__ __launch_bounds__(256) void k5b(const float* __restrict__ si2, const float* __restrict__ sj2,
    const float* __restrict__ sk2, const float* __restrict__ e2w,
    const float* __restrict__ A4, const float* __restrict__ A5, const float* __restrict__ A6,
    const float* __restrict__ A7,
    float* __restrict__ A1p, float* __restrict__ A2t, float* __restrict__ Cc){
  int which = blockIdx.y;
  int blk = blockIdx.x, b = blk/40, f = blk%40, tid = threadIdx.x;
  __shared__ float src[2560];
  __shared__ float wt[32*65];
  const float* S = (which == 0) ? si2 : (which == 1) ? sj2 : sk2;
  int wop = which + 1;
  for (int idx = tid; idx < 2560; idx += 256) src[idx] = S[(size_t)(b*40+f)*2560 + idx];
  for (int idx = tid; idx < 2048; idx += 256){
    int o = idx >> 6, d = idx & 63;
    wt[o*65 + d] = e2w[wop*2048 + d*32 + o];
  }
  __syncthreads();
  for (int idx = tid; idx < 1280; idx += 256){
    int r = idx >> 5, o = idx & 31;
    float a = 0.f;
    for (int d = 0; d < 64; ++d) a += src[r*64 + d] * wt[o*65 + d];
    size_t oi = ((size_t)(b*40+f)*40 + r)*32 + o;
    if (which == 0)      A1p[oi] = a + A4[(b*40+r)*32 + o];
    else if (which == 1) A2t[oi] = a;
    else                 Cc[oi]  = a + A5[(b*40+r)*32 + o] + A6[(b*40+f)*32 + o] + A7[b*32 + o];
  }
}

// ---------------- mode2: layer-2 evaluation; block=(b,j), loop i ----------------
__global__ __launch_bounds__(256, 2) void kh2(
    const u16* __restrict__ e_b, const u16* __restrict__ Vt, const float* __restrict__ Q3c,
    const u16* __restrict__ W2T0,
    const float* __restrict__ A1p, const float* __restrict__ A2t, const float* __restrict__ Cc,
    float* __restrict__ out_part)
{
  __shared__ __align__(16) u16 sU[48*LSTR];
  __shared__ __align__(16) u16 sB1[64*LSTR];
  __shared__ __align__(16) u16 sB0[64*LSTR];
  __shared__ __align__(16) u16 sW2[32*LSTR];
  __shared__ __align__(16) u16 sH[48*LSTR];
  const int tid = threadIdx.x;
  const int b = blockIdx.x / 40, fix = blockIdx.x % 40;   // fix = j
  const int wave = tid >> 6, lane = tid & 63, l15 = lane & 15, quad = lane >> 4;

  for (int idx = tid; idx < 1536; idx += 256){
    int r = idx >> 5, c = idx & 31;
    unsigned v = (r < 40) ? ((const unsigned*)e_b)[(b*40 + r)*32 + c] : 0u;
    ((unsigned*)(sU + r*LSTR))[c] = v;
  }
  const unsigned* eg = (const unsigned*)(e_b + (size_t)(b*40 + fix)*64);
  const unsigned* Vb = (const unsigned*)(Vt + (size_t)b*16384);
  for (int idx = tid; idx < 2048; idx += 256){
    int o = idx >> 5, d2 = idx & 31;
    unsigned eu = eg[d2];
    unsigned v0 = Vb[o*32 + d2];
    unsigned vA = Vb[2*2048 + o*32 + d2];
    unsigned vB = Vb[1*2048 + o*32 + d2];
    unsigned v3 = Vb[3*2048 + o*32 + d2];
    float e0 = bflo(eu), e1 = bfhi(eu);
    ((unsigned*)(sB1 + o*LSTR))[d2] = pack2(e0*bflo(v0)+bflo(vA), e1*bfhi(v0)+bfhi(vA));
    ((unsigned*)(sB0 + o*LSTR))[d2] = pack2(e0*bflo(vB)+bflo(v3), e1*bfhi(vB)+bfhi(v3));
  }
  for (int idx = tid; idx < 1024; idx += 256){
    int o = idx >> 5, c = idx & 31;
    ((unsigned*)(sW2 + o*LSTR))[c] = ((const unsigned*)W2T0)[idx];
  }
  __syncthreads();

  float uf[3][2][8];
  f4_t Y0[3];
  bf8_t b1f[2], wf[2];
  {
    bf8_t b0f[2];
    #pragma unroll
    for (int ks = 0; ks < 2; ++ks){
      b1f[ks] = *(const bf8_t*)&sB1[(wave*16 + l15)*LSTR + ks*32 + quad*8];
      b0f[ks] = *(const bf8_t*)&sB0[(wave*16 + l15)*LSTR + ks*32 + quad*8];
      wf[ks]  = *(const bf8_t*)&sW2[((wave&1)*16 + l15)*LSTR + ks*32 + quad*8];
    }
    #pragma unroll
    for (int m = 0; m < 3; ++m){
      f4_t a = (f4_t){0.f,0.f,0.f,0.f};
      #pragma unroll
      for (int ks = 0; ks < 2; ++ks){
        bf8_t ua = *(const bf8_t*)&sU[(m*16 + l15)*LSTR + ks*32 + quad*8];
        unpack8(ua, uf[m][ks]);
        a = __builtin_amdgcn_mfma_f32_16x16x32_bf16(ua, b0f[ks], a, 0, 0, 0);
      }
      Y0[m] = a;
    }
  }

  const int o1 = wave*16 + l15;
  const int o2 = (wave & 1)*16 + l15;
  float pa1[3][4];
  if (wave < 2){
    #pragma unroll
    for (int m = 0; m < 3; ++m)
      #pragma unroll
      for (int r = 0; r < 4; ++r){
        int kk = m*16 + quad*4 + r;
        pa1[m][r] = (kk < 40) ? A1p[((size_t)((b*40 + fix)*40 + kk))*32 + o2] : 0.f;
      }
  }
  float psum = 0.f;

  for (int l = 0; l < 40; ++l){
    float cadd = Q3c[((size_t)(b*1600 + l*40 + fix))*64 + o1];
    float ccv = 0.f;
    float a2[3][4];
    if (wave < 2){
      ccv = Cc[((size_t)((b*40 + l)*40 + fix))*32 + o2];
      #pragma unroll
      for (int m = 0; m < 3; ++m)
        #pragma unroll
        for (int r = 0; r < 4; ++r){
          int kk = m*16 + quad*4 + r;
          a2[m][r] = (kk < 40) ? A2t[((size_t)((b*40 + l)*40 + kk))*32 + o2] : 0.f;
        }
    }
    float ef[2][8];
    #pragma unroll
    for (int ks = 0; ks < 2; ++ks){
      bf8_t ev = *(const bf8_t*)&sU[l*LSTR + ks*32 + quad*8];
      unpack8(ev, ef[ks]);
    }
    f4_t acc[3];
    #pragma unroll
    for (int m = 0; m < 3; ++m){
      f4_t a = Y0[m];
      a = __builtin_amdgcn_mfma_f32_16x16x32_bf16(mul_frag(uf[m][0], ef[0]), b1f[0], a, 0, 0, 0);
      a = __builtin_amdgcn_mfma_f32_16x16x32_bf16(mul_frag(uf[m][1], ef[1]), b1f[1], a, 0, 0, 0);
      acc[m] = a;
    }
    #pragma unroll
    for (int m = 0; m < 3; ++m)
      #pragma unroll
      for (int r = 0; r < 4; ++r){
        int kk = m*16 + quad*4 + r;
        float h = acc[m][r] + cadd;
        sH[kk*LSTR + o1] = (kk < 40 && h > 0.f) ? f2bf(h) : (u16)0;
      }
    __syncthreads();
    if (wave < 2){
      f4_t y[3];
      y[0] = (f4_t){0.f,0.f,0.f,0.f}; y[1] = y[0]; y[2] = y[0];
      #pragma unroll
      for (int ks = 0; ks < 2; ++ks){
        #pragma unroll
        for (int m = 0; m < 3; ++m){
          bf8_t ha = *(const bf8_t*)&sH[(m*16 + l15)*LSTR + ks*32 + quad*8];
          y[m] = __builtin_amdgcn_mfma_f32_16x16x32_bf16(ha, wf[ks], y[m], 0, 0, 0);
        }
      }
      #pragma unroll
      for (int m = 0; m < 3; ++m)
        #pragma unroll
        for (int r = 0; r < 4; ++r){
          int kk = m*16 + quad*4 + r;
          if (kk < 40){
            float v = y[m][r] + pa1[m][r] + a2[m][r] + ccv;
            psum += v > 0.f ? v : 0.f;
          }
        }
    }
    __syncthreads();
  }
  psum += __shfl_xor(psum, 16);
  psum += __shfl_xor(psum, 32);
  if (wave < 2 && lane < 16)
    out_part[(b*40 + fix)*32 + o2] = psum;
}

// ---------------- final: sum_j out_part, relu, dot out_w ----------------
__global__ __launch_bounds__(64) void k7(const float* __restrict__ out_part, const float* __restrict__ ow,
                                         const float* __restrict__ ob, float* __restrict__ out){
  int b = threadIdx.x;
  if (b < 16){
    float res = ob[0];
    for (int o = 0; o < 32; ++o){
      float s = 0.f;
      for (int j = 0; j < 40; ++j) s += out_part[(b*40+j)*32 + o];
      s = s > 0.f ? s : 0.f;
      res += s * ow[o];
    }
    out[b] = res;
  }
}

extern "C" void kernel_launch(void* const* d_in, const int* in_sizes, int n_in,
                              void* d_out, int out_size, void* d_ws, size_t ws_size,
                              hipStream_t stream){
  const float* x    = (const float*)d_in[0];
  const float* c1w  = (const float*)d_in[1];
  const float* c1b  = (const float*)d_in[2];
  const float* c2w  = (const float*)d_in[3];
  const float* c2b  = (const float*)d_in[4];
  const float* fcw  = (const float*)d_in[5];
  const float* fcb  = (const float*)d_in[6];
  const float* e1w  = (const float*)d_in[7];
  const float* e1b  = (const float*)d_in[8];
  const float* e2w  = (const float*)d_in[9];
  const float* e2b  = (const float*)d_in[10];
  const float* ow   = (const float*)d_in[11];
  const float* ob   = (const float*)d_in[12];

  char* ws = (char*)d_ws;
  size_t off = 0;
  auto alloc = [&](size_t bytes) -> void* {
    void* p = ws + off;
    off += (bytes + 255) & ~(size_t)255;
    return p;
  };
  u16*   z1t  = (u16*)  alloc((size_t)640*4608*2);
  u16*   wt2  = (u16*)  alloc(51200*2);
  u16*   fcwT = (u16*)  alloc(65536*2);
  u16*   z2g  = (u16*)  alloc((size_t)640*1024*2);
  float* e_f  = (float*)alloc(40960*4);
  u16*   e_b  = (u16*)  alloc(40960*2);
  float* Sg   = (float*)alloc(1024*4);
  u16*   Vt   = (u16*)  alloc((size_t)16*16384*2);
  float* c0   = (float*)alloc(1024*4);
  float* P5   = (float*)alloc(40960*4);
  float* P6   = (float*)alloc(40960*4);
  u16*   W2T0 = (u16*)  alloc(2048*2);
  float* Q3c  = (float*)alloc((size_t)1638400*4);
  float* si2  = (float*)alloc((size_t)1638400*4);
  float* sj2  = (float*)alloc((size_t)1638400*4);
  float* sk2  = (float*)alloc((size_t)1638400*4);
  float* A4   = (float*)alloc(20480*4);
  float* A5   = (float*)alloc(20480*4);
  float* A6   = (float*)alloc(20480*4);
  float* A7   = (float*)alloc(512*4);
  float* A1p  = (float*)alloc((size_t)819200*4);
  float* A2t  = (float*)alloc((size_t)819200*4);
  float* Cc   = (float*)alloc((size_t)819200*4);
  float* op   = (float*)alloc(20480*4);
  (void)in_sizes; (void)n_in; (void)out_size; (void)ws_size;

  kwp    <<<32,  256, 0, stream>>>(c2w, fcw, wt2, fcwT);
  kconv1 <<<640, 256, 0, stream>>>(x, c1w, c1b, z1t);
  kconv2m<<<640, 256, 0, stream>>>(z1t, wt2, c2b, z2g);
  kfc    <<<40,  256, 0, stream>>>(z2g, fcwT, fcb, e_f, e_b);
  kprep  <<<16,  256, 0, stream>>>(e_f, e1w, e1b, e2w, Sg, Vt, c0, P5, P6, W2T0);
  kq3    <<<640, 256, 0, stream>>>(e_f, Sg, e1w, P5, P6, c0, Q3c);
  kh01   <<<dim3(640,2), 256, 0, stream>>>(e_b, Vt, Q3c, si2, sj2, sk2);
  k5a    <<<16,  256, 0, stream>>>(si2, sj2, e2w, e2b, A4, A5, A6, A7);
  k5b    <<<dim3(640,3), 256, 0, stream>>>(si2, sj2, sk2, e2w, A4, A5, A6, A7, A1p, A2t, Cc);
  kh2    <<<640, 256, 0, stream>>>(e_b, Vt, Q3c, W2T0, A1p, A2t, Cc, op);
  k7     <<<1, 64, 0, stream>>>(op, ow, ob, (float*)d_out);
}

// Round 4
// 397.285 us; speedup vs baseline: 2.5358x; 1.0420x over previous
//
#include <hip/hip_runtime.h>
#include <hip/hip_bf16.h>

// UniqueEq3Net: conv stack -> e(640,64); t = e⊗e⊗e never materialized.
// conv2 = 25 shifted K=32 MFMA GEMMs over channels-last z1t (no im2col).
// Layer1 (transposed MFMA): h^T[o][k] = Σ_d (B1⊙e_l)[d,o]·U[k,d] + Y0 + cadd
//   (modulation folded into the SHARED A-operand: 2 frags/iter, not 6)
// kh01: barrier-free l-loop, register accumulation, float4 epilogue.
// kh2: double-buffered sH, 1 barrier/iter, phase-2 across 3 waves.

typedef unsigned short u16;
typedef __attribute__((ext_vector_type(8))) short bf8_t;   // 8 bf16 (4 VGPRs)
typedef __attribute__((ext_vector_type(4))) float f4_t;

#define LSTR 72   // padded LDS row stride (u16): 144B rows, 16B-aligned

__device__ inline u16 f2bf(float f){
  union { float f; unsigned u; } v; v.f = f;
  unsigned r = v.u + 0x7fffu + ((v.u >> 16) & 1u);
  return (u16)(r >> 16);
}
__device__ inline float bflo(unsigned u){ union { unsigned x; float f; } v; v.x = u << 16; return v.f; }
__device__ inline float bfhi(unsigned u){ union { unsigned x; float f; } v; v.x = u & 0xffff0000u; return v.f; }
__device__ inline unsigned pack2(float a, float b){ return (unsigned)f2bf(a) | ((unsigned)f2bf(b) << 16); }
__device__ inline void unpack8(bf8_t x, float* o){
  union { bf8_t v; unsigned u[4]; } q; q.v = x;
  #pragma unroll
  for (int p = 0; p < 4; ++p){ o[2*p] = bflo(q.u[p]); o[2*p+1] = bfhi(q.u[p]); }
}
// RN (round-to-nearest) modulated fragment: unbiased, buys absmax headroom
__device__ inline bf8_t mul_frag(const float* a, const float* e){
  union { bf8_t v; unsigned u[4]; } r;
  #pragma unroll
  for (int p = 0; p < 4; ++p)
    r.u[p] = pack2(a[2*p]*e[2*p], a[2*p+1]*e[2*p+1]);
  return r.v;
}

// ---------------- weight prep: wt2[tap][co][ci] bf16, fcwT[o][k] bf16 ----------------
__global__ __launch_bounds__(256) void kwp(const float* __restrict__ w2, const float* __restrict__ fcw,
                                           u16* __restrict__ wt2, u16* __restrict__ fcwT){
  int tid = blockIdx.x*256 + threadIdx.x, stride = gridDim.x*256;
  for (int i = tid; i < 51200; i += stride){
    int tap = i >> 11, rc = i & 2047, co = rc >> 5, ci = rc & 31;
    wt2[i] = f2bf(w2[co*800 + ci*25 + tap]);
  }
  for (int i = tid; i < 65536; i += stride){
    int o = i >> 10, k = i & 1023;
    fcwT[i] = f2bf(fcw[k*64 + o]);
  }
}

// ---------------- conv1 + pool -> z1t (640, 144 pos, 32 ci) bf16 channels-last ----------------
__global__ __launch_bounds__(256) void kconv1(const float* __restrict__ x, const float* __restrict__ w1,
                                              const float* __restrict__ b1, u16* __restrict__ z1t){
  __shared__ float simg[784];
  int img = blockIdx.x, tid = threadIdx.x;
  for (int i = tid; i < 784; i += 256) simg[i] = x[img*784 + i];
  const int c = tid & 31;
  float wc[25];
  #pragma unroll
  for (int t = 0; t < 25; ++t) wc[t] = w1[c*25 + t];
  const float bb = b1[c];
  __syncthreads();
  #pragma unroll 2
  for (int it = 0; it < 18; ++it){
    int p = (tid >> 5) + it*8;          // 0..143
    int py = p / 12, px = p % 12;
    float patch[36];
    const float* sp = &simg[2*py*28 + 2*px];
    #pragma unroll
    for (int yy = 0; yy < 6; ++yy)
      #pragma unroll
      for (int xx = 0; xx < 6; ++xx) patch[yy*6+xx] = sp[yy*28+xx];
    float mx = -1e30f;
    #pragma unroll
    for (int sy = 0; sy < 2; ++sy)
    #pragma unroll
    for (int sx = 0; sx < 2; ++sx){
      float s = bb;
      #pragma unroll
      for (int dy = 0; dy < 5; ++dy)
        #pragma unroll
        for (int dx = 0; dx < 5; ++dx)
          s += patch[(sy+dy)*6 + sx+dx] * wc[dy*5+dx];
      mx = fmaxf(mx, s);
    }
    z1t[(size_t)img*4608 + p*32 + c] = f2bf(fmaxf(mx, 0.f));
  }
}

// ---------------- conv2 (MFMA, 25 shifted K=32 GEMMs) + pool -> z2g (640,1024) bf16 ----------------
__global__ __launch_bounds__(256) void kconv2m(const u16* __restrict__ z1t, const u16* __restrict__ wt2,
                                               const float* __restrict__ b2, u16* __restrict__ z2g){
  __shared__ __align__(16) u16 sz[4608];   // [pos 144][ci 32]
  __shared__ __align__(16) u16 sz2[1024];
  int img = blockIdx.x, tid = threadIdx.x;
  for (int i = tid; i < 576; i += 256)
    ((uint4*)sz)[i] = ((const uint4*)(z1t + (size_t)img*4608))[i];
  __syncthreads();
  const int wave = tid >> 6, lane = tid & 63, l15 = lane & 15, quad = lane >> 4;
  const int y = wave*2 + (l15 >> 3), x = l15 & 7;   // output pos = wave*16+l15 on 8x8
  f4_t acc[4];
  acc[0] = (f4_t){0.f,0.f,0.f,0.f}; acc[1] = acc[0]; acc[2] = acc[0]; acc[3] = acc[0];
  #pragma unroll
  for (int dy = 0; dy < 5; ++dy)
    #pragma unroll
    for (int dx = 0; dx < 5; ++dx){
      const int tap = dy*5 + dx;
      bf8_t af = *(const bf8_t*)&sz[((y+dy)*12 + (x+dx))*32 + quad*8];
      const u16* wp = wt2 + tap*2048 + l15*32 + quad*8;
      #pragma unroll
      for (int nt = 0; nt < 4; ++nt){
        bf8_t bf = *(const bf8_t*)(wp + nt*512);
        acc[nt] = __builtin_amdgcn_mfma_f32_16x16x32_bf16(af, bf, acc[nt], 0, 0, 0);
      }
    }
  #pragma unroll
  for (int nt = 0; nt < 4; ++nt){
    int co = nt*16 + l15;
    float v0 = fmaxf(acc[nt][0], acc[nt][1]);
    float v1 = fmaxf(acc[nt][2], acc[nt][3]);
    v0 = fmaxf(v0, __shfl_xor(v0, 32));
    v1 = fmaxf(v1, __shfl_xor(v1, 32));
    if (quad < 2){
      float bb = b2[co];
      sz2[co*16 + wave*4 + quad*2 + 0] = f2bf(fmaxf(v0 + bb, 0.f));
      sz2[co*16 + wave*4 + quad*2 + 1] = f2bf(fmaxf(v1 + bb, 0.f));
    }
  }
  __syncthreads();
  if (tid < 128) ((uint4*)(z2g + (size_t)img*1024))[tid] = ((const uint4*)sz2)[tid];
}

// ---------------- fc: e = relu(z2g @ fcw + fcb)  (MFMA, M=640,K=1024,N=64) ----------------
__global__ __launch_bounds__(256) void kfc(const u16* __restrict__ z2g, const u16* __restrict__ fcwT,
                                           const float* __restrict__ fcb,
                                           float* __restrict__ e_f, u16* __restrict__ e_b){
  __shared__ __align__(16) u16 sA[16*1032];
  int img0 = blockIdx.x*16, tid = threadIdx.x;
  for (int i = tid; i < 2048; i += 256){
    int row = i >> 7, c16 = i & 127;
    ((uint4*)(sA + row*1032))[c16] = ((const uint4*)(z2g + (size_t)(img0+row)*1024))[c16];
  }
  __syncthreads();
  const int wave = tid >> 6, lane = tid & 63, l15 = lane & 15, quad = lane >> 4;
  const int o = wave*16 + l15;
  f4_t acc = (f4_t){0.f,0.f,0.f,0.f};
  #pragma unroll 8
  for (int ks = 0; ks < 32; ++ks){
    bf8_t af = *(const bf8_t*)&sA[l15*1032 + ks*32 + quad*8];
    bf8_t bf = *(const bf8_t*)(fcwT + (size_t)o*1024 + ks*32 + quad*8);
    acc = __builtin_amdgcn_mfma_f32_16x16x32_bf16(af, bf, acc, 0, 0, 0);
  }
  const float bb = fcb[o];
  #pragma unroll
  for (int r = 0; r < 4; ++r){
    int img = img0 + quad*4 + r;
    float v = fmaxf(acc[r] + bb, 0.f);
    e_f[img*64 + o] = v;
    e_b[img*64 + o] = f2bf(v);
  }
}

// ---------------- per-b precompute: S, Vt(bf16 x4), c0, P5, P6, W2T0 ----------------
__global__ __launch_bounds__(256) void kprep(const float* __restrict__ e_f, const float* __restrict__ e1w,
    const float* __restrict__ e1b, const float* __restrict__ e2w,
    float* __restrict__ Sg, u16* __restrict__ Vt, float* __restrict__ c0,
    float* __restrict__ P5, float* __restrict__ P6, u16* __restrict__ W2T0){
  int b = blockIdx.x, tid = threadIdx.x;
  __shared__ float se[2560];
  __shared__ float S[64], S2[64], S3[64];
  for (int i = tid; i < 2560; i += 256) se[i] = e_f[b*2560 + i];
  __syncthreads();
  if (tid < 64){
    float s = 0.f;
    for (int i = 0; i < 40; ++i) s += se[i*64 + tid];
    S[tid] = s; S2[tid] = s*s; S3[tid] = s*s*s; Sg[b*64 + tid] = s;
  }
  __syncthreads();
  for (int idx = tid; idx < 16384; idx += 256){
    int m = idx >> 12, rc = idx & 4095, o = rc >> 6, d = rc & 63;
    float v;
    if (m == 0)      v = e1w[d*64 + o];
    else if (m == 1) v = S[d] * e1w[4096  + d*64 + o];
    else if (m == 2) v = S[d] * e1w[8192  + d*64 + o];
    else             v = S2[d] * e1w[16384 + d*64 + o];
    Vt[(size_t)b*16384 + idx] = f2bf(v);
  }
  if (tid < 64){
    float a = e1b[tid];
    for (int d = 0; d < 64; ++d) a += S3[d] * e1w[7*4096 + d*64 + tid];
    c0[b*64 + tid] = a;
  }
  for (int idx = tid; idx < 2560; idx += 256){
    int j = idx >> 6, o = idx & 63;
    float a5 = 0.f, a6 = 0.f;
    for (int d = 0; d < 64; ++d){
      float es = se[j*64 + d] * S2[d];
      a5 += es * e1w[5*4096 + d*64 + o];
      a6 += es * e1w[6*4096 + d*64 + o];
    }
    P5[(b*40+j)*64 + o] = a5;
    P6[(b*40+j)*64 + o] = a6;
  }
  if (b == 0){
    for (int idx = tid; idx < 2048; idx += 256){
      int o = idx >> 6, d = idx & 63;
      W2T0[o*64 + d] = f2bf(e2w[d*32 + o]);
    }
  }
}

// ---------------- Q3c[b,i,j,o] ----------------
__global__ __launch_bounds__(256) void kq3(const float* __restrict__ e_f, const float* __restrict__ Sg,
    const float* __restrict__ e1w, const float* __restrict__ P5, const float* __restrict__ P6,
    const float* __restrict__ c0, float* __restrict__ Q3c){
  int blk = blockIdx.x, b = blk/40, i = blk%40, tid = threadIdx.x;
  __shared__ float w3[4096];
  __shared__ float se[2560];
  __shared__ float t3[64];
  for (int idx = tid; idx < 4096; idx += 256) w3[idx] = e1w[12288 + idx];
  for (int idx = tid; idx < 2560; idx += 256) se[idx] = e_f[b*2560 + idx];
  __syncthreads();
  if (tid < 64) t3[tid] = se[i*64 + tid] * Sg[b*64 + tid];
  __syncthreads();
  for (int idx = tid; idx < 2560; idx += 256){
    int j = idx >> 6, o = idx & 63;
    float a = 0.f;
    for (int d = 0; d < 64; ++d) a += t3[d] * se[j*64 + d] * w3[d*64 + o];
    Q3c[((size_t)(b*40+i)*40 + j)*64 + o] =
        a + P5[(b*40+j)*64 + o] + P6[(b*40+i)*64 + o] + c0[b*64 + o];
  }
}

// ---------------- layer-1 reduction passes (modes 0 & 1), transposed MFMA, barrier-free ----------------
__global__ __launch_bounds__(256, 4) void kh01(
    const u16* __restrict__ e_b, const u16* __restrict__ Vt, const float* __restrict__ Q3c,
    float* __restrict__ si2, float* __restrict__ sj2, float* __restrict__ sk2)
{
  __shared__ __align__(16) u16 sU[48*LSTR];
  __shared__ __align__(16) u16 sB1[64*LSTR];
  __shared__ __align__(16) u16 sB0[64*LSTR];
  const int tid = threadIdx.x;
  const int b = blockIdx.x / 40, fix = blockIdx.x % 40;
  const int mode = blockIdx.y;                 // 0: fix=j loop i -> si2,sk2 ; 1: fix=i loop j -> sj2
  const int wave = tid >> 6, lane = tid & 63, l15 = lane & 15, quad = lane >> 4;

  for (int idx = tid; idx < 1536; idx += 256){
    int r = idx >> 5, c = idx & 31;
    unsigned v = (r < 40) ? ((const unsigned*)e_b)[(b*40 + r)*32 + c] : 0u;
    ((unsigned*)(sU + r*LSTR))[c] = v;
  }
  const unsigned* eg = (const unsigned*)(e_b + (size_t)(b*40 + fix)*64);
  const unsigned* Vb = (const unsigned*)(Vt + (size_t)b*16384);
  for (int idx = tid; idx < 2048; idx += 256){
    int o = idx >> 5, d2 = idx & 31;
    unsigned eu = eg[d2];
    unsigned v0 = Vb[o*32 + d2];
    unsigned vA = Vb[(2-mode)*2048 + o*32 + d2];
    unsigned vB = Vb[(1+mode)*2048 + o*32 + d2];
    unsigned v3 = Vb[3*2048 + o*32 + d2];
    float e0 = bflo(eu), e1 = bfhi(eu);
    ((unsigned*)(sB1 + o*LSTR))[d2] = pack2(e0*bflo(v0)+bflo(vA), e1*bfhi(v0)+bfhi(vA));
    ((unsigned*)(sB0 + o*LSTR))[d2] = pack2(e0*bflo(vB)+bflo(v3), e1*bfhi(vB)+bfhi(v3));
  }
  __syncthreads();

  // preload: U k-tiles (bf8), B1 unpacked (for per-l modulation), Y0 = (B0^T)·U
  bf8_t ua[3][2];
  float b1uf[2][8];
  f4_t Y0[3];
  {
    bf8_t b0f[2], b1f[2];
    #pragma unroll
    for (int ks = 0; ks < 2; ++ks){
      b1f[ks] = *(const bf8_t*)&sB1[(wave*16 + l15)*LSTR + ks*32 + quad*8];
      b0f[ks] = *(const bf8_t*)&sB0[(wave*16 + l15)*LSTR + ks*32 + quad*8];
      unpack8(b1f[ks], b1uf[ks]);
    }
    #pragma unroll
    for (int n = 0; n < 3; ++n){
      f4_t a = (f4_t){0.f,0.f,0.f,0.f};
      #pragma unroll
      for (int ks = 0; ks < 2; ++ks){
        ua[n][ks] = *(const bf8_t*)&sU[(n*16 + l15)*LSTR + ks*32 + quad*8];
        a = __builtin_amdgcn_mfma_f32_16x16x32_bf16(b0f[ks], ua[n][ks], a, 0, 0, 0);
      }
      Y0[n] = a;
    }
  }

  const int obase = wave*16 + quad*4;          // thread's 4 contiguous o's
  f4_t sacc[3];
  sacc[0] = (f4_t){0.f,0.f,0.f,0.f}; sacc[1] = sacc[0]; sacc[2] = sacc[0];

  for (int l = 0; l < 40; ++l){
    const int qidx = mode ? (fix*40 + l) : (l*40 + fix);
    f4_t cadd = *(const f4_t*)&Q3c[((size_t)(b*1600 + qidx))*64 + obase];
    bf8_t mb[2];
    #pragma unroll
    for (int ks = 0; ks < 2; ++ks){
      bf8_t ev = *(const bf8_t*)&sU[l*LSTR + ks*32 + quad*8];
      float ef[8]; unpack8(ev, ef);
      mb[ks] = mul_frag(b1uf[ks], ef);
    }
    f4_t khs = (f4_t){0.f,0.f,0.f,0.f};
    #pragma unroll
    for (int n = 0; n < 3; ++n){
      f4_t a = Y0[n];
      a = __builtin_amdgcn_mfma_f32_16x16x32_bf16(mb[0], ua[n][0], a, 0, 0, 0);
      a = __builtin_amdgcn_mfma_f32_16x16x32_bf16(mb[1], ua[n][1], a, 0, 0, 0);
      const bool valid = (n < 2) | (l15 < 8);   // k = n*16+l15 < 40
      #pragma unroll
      for (int r = 0; r < 4; ++r){
        float h = fmaxf(a[r] + cadd[r], 0.f);
        h = valid ? h : 0.f;
        sacc[n][r] += h;
        khs[r] += h;
      }
    }
    if (mode == 0){
      #pragma unroll
      for (int r = 0; r < 4; ++r){
        float v = khs[r];
        v += __shfl_xor(v, 1); v += __shfl_xor(v, 2);
        v += __shfl_xor(v, 4); v += __shfl_xor(v, 8);
        khs[r] = v;
      }
      if (l15 == 0)
        *(f4_t*)&sk2[((size_t)((b*40 + l)*40 + fix))*64 + obase] = khs;
    }
  }
  float* dst = mode ? sj2 : si2;
  #pragma unroll
  for (int n = 0; n < 3; ++n){
    int k = n*16 + l15;
    if (k < 40)
      *(f4_t*)&dst[((size_t)((b*40 + fix)*40 + k))*64 + obase] = sacc[n];
  }
}

// ---------------- pair sums + small addends ----------------
__global__ __launch_bounds__(256) void k5a(const float* __restrict__ si2, const float* __restrict__ sj2,
    const float* __restrict__ e2w, const float* __restrict__ e2b,
    float* __restrict__ A4, float* __restrict__ A5, float* __restrict__ A6, float* __restrict__ A7){
  int b = blockIdx.x, tid = threadIdx.x;
  __shared__ float ssij[2560], ssik[2560], ssjk[2560], ss2[64];
  for (int idx = tid; idx < 2560; idx += 256){
    int k = idx >> 6, d = idx & 63;
    float a = 0.f;
    for (int j = 0; j < 40; ++j) a += si2[((size_t)(b*40+j)*40 + k)*64 + d];
    ssij[idx] = a;
  }
  for (int idx = tid; idx < 2560; idx += 256){
    int j = idx >> 6, d = idx & 63;
    float a = 0.f, c = 0.f;
    const float* p = &si2[(size_t)(b*40+j)*2560 + d];
    const float* q = &sj2[(size_t)(b*40+j)*2560 + d];
    for (int k = 0; k < 40; ++k){ a += p[k*64]; c += q[k*64]; }
    ssik[idx] = a;
    ssjk[idx] = c;
  }
  __syncthreads();
  if (tid < 64){
    float a = 0.f;
    for (int k = 0; k < 40; ++k) a += ssij[k*64 + tid];
    ss2[tid] = a;
  }
  __syncthreads();
  for (int idx = tid; idx < 1280; idx += 256){
    int k = idx >> 5, o = idx & 31;
    float a4 = 0.f, a5 = 0.f, a6 = 0.f;
    for (int d = 0; d < 64; ++d){
      a4 += ssij[k*64+d] * e2w[4*2048 + d*32 + o];
      a5 += ssik[k*64+d] * e2w[5*2048 + d*32 + o];
      a6 += ssjk[k*64+d] * e2w[6*2048 + d*32 + o];
    }
    A4[(b*40+k)*32 + o] = a4;
    A5[(b*40+k)*32 + o] = a5;
    A6[(b*40+k)*32 + o] = a6;
  }
  if (tid < 32){
    float a = e2b[tid];
    for (int d = 0; d < 64; ++d) a += ss2[d] * e2w[7*2048 + d*32 + tid];
    A7[b*32 + tid] = a;
  }
}

// ---------------- big addends: A1p=si2@W'1+A4, A2t=sj2@W'2, Cc=sk2@W'3+A5+A6+A7 ----------------
__global__ __launch_bounds__(256) void k5b(const float* __restrict__ si2, const float* __restrict__ sj2,
    const float* __restrict__ sk2, const float* __restrict__ e2w,
    const float* __restrict__ A4, const float* __restrict__ A5, const float* __restrict__ A6,
    const float* __restrict__ A7,
    float* __restrict__ A1p, float* __restrict__ A2t, float* __restrict__ Cc){
  int which = blockIdx.y;
  int blk = blockIdx.x, b = blk/40, f = blk%40, tid = threadIdx.x;
  __shared__ float src[2560];
  __shared__ float wt[32*65];
  const float* S = (which == 0) ? si2 : (which == 1) ? sj2 : sk2;
  int wop = which + 1;
  for (int idx = tid; idx < 2560; idx += 256) src[idx] = S[(size_t)(b*40+f)*2560 + idx];
  for (int idx = tid; idx < 2048; idx += 256){
    int o = idx >> 6, d = idx & 63;
    wt[o*65 + d] = e2w[wop*2048 + d*32 + o];
  }
  __syncthreads();
  for (int idx = tid; idx < 1280; idx += 256){
    int r = idx >> 5, o = idx & 31;
    float a = 0.f;
    for (int d = 0; d < 64; ++d) a += src[r*64 + d] * wt[o*65 + d];
    size_t oi = ((size_t)(b*40+f)*40 + r)*32 + o;
    if (which == 0)      A1p[oi] = a + A4[(b*40+r)*32 + o];
    else if (which == 1) A2t[oi] = a;
    else                 Cc[oi]  = a + A5[(b*40+r)*32 + o] + A6[(b*40+f)*32 + o] + A7[b*32 + o];
  }
}

// ---------------- mode2: layer-2 evaluation; block=(b,j), loop i; dbuf sH, 1 barrier/iter ----------------
__global__ __launch_bounds__(256, 3) void kh2(
    const u16* __restrict__ e_b, const u16* __restrict__ Vt, const float* __restrict__ Q3c,
    const u16* __restrict__ W2T0,
    const float* __restrict__ A1p, const float* __restrict__ A2t, const float* __restrict__ Cc,
    float* __restrict__ out_part)
{
  __shared__ __align__(16) u16 sU[48*LSTR];
  __shared__ __align__(16) u16 sB1[64*LSTR];
  __shared__ __align__(16) u16 sB0[64*LSTR];
  __shared__ __align__(16) u16 sW2[32*LSTR];
  __shared__ __align__(16) u16 sH[2][48*LSTR];
  __shared__ float soacc[32];
  const int tid = threadIdx.x;
  const int b = blockIdx.x / 40, fix = blockIdx.x % 40;   // fix = j
  const int wave = tid >> 6, lane = tid & 63, l15 = lane & 15, quad = lane >> 4;

  for (int idx = tid; idx < 1536; idx += 256){
    int r = idx >> 5, c = idx & 31;
    unsigned v = (r < 40) ? ((const unsigned*)e_b)[(b*40 + r)*32 + c] : 0u;
    ((unsigned*)(sU + r*LSTR))[c] = v;
  }
  const unsigned* eg = (const unsigned*)(e_b + (size_t)(b*40 + fix)*64);
  const unsigned* Vb = (const unsigned*)(Vt + (size_t)b*16384);
  for (int idx = tid; idx < 2048; idx += 256){
    int o = idx >> 5, d2 = idx & 31;
    unsigned eu = eg[d2];
    unsigned v0 = Vb[o*32 + d2];
    unsigned vA = Vb[2*2048 + o*32 + d2];
    unsigned vB = Vb[1*2048 + o*32 + d2];
    unsigned v3 = Vb[3*2048 + o*32 + d2];
    float e0 = bflo(eu), e1 = bfhi(eu);
    ((unsigned*)(sB1 + o*LSTR))[d2] = pack2(e0*bflo(v0)+bflo(vA), e1*bfhi(v0)+bfhi(vA));
    ((unsigned*)(sB0 + o*LSTR))[d2] = pack2(e0*bflo(vB)+bflo(v3), e1*bfhi(vB)+bfhi(v3));
  }
  for (int idx = tid; idx < 1024; idx += 256){
    int o = idx >> 5, c = idx & 31;
    ((unsigned*)(sW2 + o*LSTR))[c] = ((const unsigned*)W2T0)[idx];
  }
  if (tid < 32) soacc[tid] = 0.f;
  __syncthreads();

  bf8_t ua[3][2];
  float b1uf[2][8];
  f4_t Y0[3];
  bf8_t wfA[2][2];
  {
    bf8_t b0f[2], b1f[2];
    #pragma unroll
    for (int ks = 0; ks < 2; ++ks){
      b1f[ks] = *(const bf8_t*)&sB1[(wave*16 + l15)*LSTR + ks*32 + quad*8];
      b0f[ks] = *(const bf8_t*)&sB0[(wave*16 + l15)*LSTR + ks*32 + quad*8];
      unpack8(b1f[ks], b1uf[ks]);
      #pragma unroll
      for (int m = 0; m < 2; ++m)
        wfA[m][ks] = *(const bf8_t*)&sW2[(m*16 + l15)*LSTR + ks*32 + quad*8];
    }
    #pragma unroll
    for (int n = 0; n < 3; ++n){
      f4_t a = (f4_t){0.f,0.f,0.f,0.f};
      #pragma unroll
      for (int ks = 0; ks < 2; ++ks){
        ua[n][ks] = *(const bf8_t*)&sU[(n*16 + l15)*LSTR + ks*32 + quad*8];
        a = __builtin_amdgcn_mfma_f32_16x16x32_bf16(b0f[ks], ua[n][ks], a, 0, 0, 0);
      }
      Y0[n] = a;
    }
  }

  const int obase = wave*16 + quad*4;          // phase-1: o's
  const int o2b   = quad*4;                    // phase-2: o2 offset within m-tile
  const int kme   = wave*16 + l15;             // phase-2: this wave's k
  const int kmc   = kme < 40 ? kme : 39;       // clamped (mask applied later)
  const bool kval = (kme < 40) & (wave < 3);
  f4_t pa1[2], psum[2];
  psum[0] = (f4_t){0.f,0.f,0.f,0.f}; psum[1] = psum[0];
  if (wave < 3){
    #pragma unroll
    for (int m = 0; m < 2; ++m)
      pa1[m] = *(const f4_t*)&A1p[((size_t)((b*40 + fix)*40 + kmc))*32 + m*16 + o2b];
  }

  for (int l = 0; l < 40; ++l){
    // early phase-2 addend loads (overlap with phase-1 compute)
    f4_t a2v[2], ccv[2];
    if (wave < 3){
      #pragma unroll
      for (int m = 0; m < 2; ++m){
        a2v[m] = *(const f4_t*)&A2t[((size_t)((b*40 + l)*40 + kmc))*32 + m*16 + o2b];
        ccv[m] = *(const f4_t*)&Cc [((size_t)((b*40 + l)*40 + fix))*32 + m*16 + o2b];
      }
    }
    f4_t cadd = *(const f4_t*)&Q3c[((size_t)(b*1600 + l*40 + fix))*64 + obase];
    bf8_t mb[2];
    #pragma unroll
    for (int ks = 0; ks < 2; ++ks){
      bf8_t ev = *(const bf8_t*)&sU[l*LSTR + ks*32 + quad*8];
      float ef[8]; unpack8(ev, ef);
      mb[ks] = mul_frag(b1uf[ks], ef);
    }
    u16* Hb = sH[l & 1];
    #pragma unroll
    for (int n = 0; n < 3; ++n){
      f4_t a = Y0[n];
      a = __builtin_amdgcn_mfma_f32_16x16x32_bf16(mb[0], ua[n][0], a, 0, 0, 0);
      a = __builtin_amdgcn_mfma_f32_16x16x32_bf16(mb[1], ua[n][1], a, 0, 0, 0);
      const bool valid = (n < 2) | (l15 < 8);
      unsigned p0 = 0, p1 = 0;
      if (valid){
        p0 = pack2(fmaxf(a[0] + cadd[0], 0.f), fmaxf(a[1] + cadd[1], 0.f));
        p1 = pack2(fmaxf(a[2] + cadd[2], 0.f), fmaxf(a[3] + cadd[3], 0.f));
      }
      uint2 pw; pw.x = p0; pw.y = p1;
      *(uint2*)&Hb[(n*16 + l15)*LSTR + obase] = pw;
    }
    __syncthreads();
    if (wave < 3){
      bf8_t hB[2];
      #pragma unroll
      for (int ks = 0; ks < 2; ++ks)
        hB[ks] = *(const bf8_t*)&Hb[(wave*16 + l15)*LSTR + ks*32 + quad*8];
      #pragma unroll
      for (int m = 0; m < 2; ++m){
        f4_t y = (f4_t){0.f,0.f,0.f,0.f};
        y = __builtin_amdgcn_mfma_f32_16x16x32_bf16(wfA[m][0], hB[0], y, 0, 0, 0);
        y = __builtin_amdgcn_mfma_f32_16x16x32_bf16(wfA[m][1], hB[1], y, 0, 0, 0);
        if (kval){
          #pragma unroll
          for (int r = 0; r < 4; ++r){
            float v = y[r] + pa1[m][r] + a2v[m][r] + ccv[m][r];
            psum[m][r] += v > 0.f ? v : 0.f;
          }
        }
      }
    }
  }
  // final reduction: sum psum over l15 lanes, atomically combine waves
  if (wave < 3){
    #pragma unroll
    for (int m = 0; m < 2; ++m)
      #pragma unroll
      for (int r = 0; r < 4; ++r){
        float v = psum[m][r];
        v += __shfl_xor(v, 1); v += __shfl_xor(v, 2);
        v += __shfl_xor(v, 4); v += __shfl_xor(v, 8);
        if (l15 == 0) atomicAdd(&soacc[m*16 + o2b + r], v);
      }
  }
  __syncthreads();
  if (tid < 32) out_part[(b*40 + fix)*32 + tid] = soacc[tid];
}

// ---------------- final: sum_j out_part, relu, dot out_w ----------------
__global__ __launch_bounds__(64) void k7(const float* __restrict__ out_part, const float* __restrict__ ow,
                                         const float* __restrict__ ob, float* __restrict__ out){
  int b = threadIdx.x;
  if (b < 16){
    float res = ob[0];
    for (int o = 0; o < 32; ++o){
      float s = 0.f;
      for (int j = 0; j < 40; ++j) s += out_part[(b*40+j)*32 + o];
      s = s > 0.f ? s : 0.f;
      res += s * ow[o];
    }
    out[b] = res;
  }
}

extern "C" void kernel_launch(void* const* d_in, const int* in_sizes, int n_in,
                              void* d_out, int out_size, void* d_ws, size_t ws_size,
                              hipStream_t stream){
  const float* x    = (const float*)d_in[0];
  const float* c1w  = (const float*)d_in[1];
  const float* c1b  = (const float*)d_in[2];
  const float* c2w  = (const float*)d_in[3];
  const float* c2b  = (const float*)d_in[4];
  const float* fcw  = (const float*)d_in[5];
  const float* fcb  = (const float*)d_in[6];
  const float* e1w  = (const float*)d_in[7];
  const float* e1b  = (const float*)d_in[8];
  const float* e2w  = (const float*)d_in[9];
  const float* e2b  = (const float*)d_in[10];
  const float* ow   = (const float*)d_in[11];
  const float* ob   = (const float*)d_in[12];

  char* ws = (char*)d_ws;
  size_t off = 0;
  auto alloc = [&](size_t bytes) -> void* {
    void* p = ws + off;
    off += (bytes + 255) & ~(size_t)255;
    return p;
  };
  u16*   z1t  = (u16*)  alloc((size_t)640*4608*2);
  u16*   wt2  = (u16*)  alloc(51200*2);
  u16*   fcwT = (u16*)  alloc(65536*2);
  u16*   z2g  = (u16*)  alloc((size_t)640*1024*2);
  float* e_f  = (float*)alloc(40960*4);
  u16*   e_b  = (u16*)  alloc(40960*2);
  float* Sg   = (float*)alloc(1024*4);
  u16*   Vt   = (u16*)  alloc((size_t)16*16384*2);
  float* c0   = (float*)alloc(1024*4);
  float* P5   = (float*)alloc(40960*4);
  float* P6   = (float*)alloc(40960*4);
  u16*   W2T0 = (u16*)  alloc(2048*2);
  float* Q3c  = (float*)alloc((size_t)1638400*4);
  float* si2  = (float*)alloc((size_t)1638400*4);
  float* sj2  = (float*)alloc((size_t)1638400*4);
  float* sk2  = (float*)alloc((size_t)1638400*4);
  float* A4   = (float*)alloc(20480*4);
  float* A5   = (float*)alloc(20480*4);
  float* A6   = (float*)alloc(20480*4);
  float* A7   = (float*)alloc(512*4);
  float* A1p  = (float*)alloc((size_t)819200*4);
  float* A2t  = (float*)alloc((size_t)819200*4);
  float* Cc   = (float*)alloc((size_t)819200*4);
  float* op   = (float*)alloc(20480*4);
  (void)in_sizes; (void)n_in; (void)out_size; (void)ws_size;

  kwp    <<<32,  256, 0, stream>>>(c2w, fcw, wt2, fcwT);
  kconv1 <<<640, 256, 0, stream>>>(x, c1w, c1b, z1t);
  kconv2m<<<640, 256, 0, stream>>>(z1t, wt2, c2b, z2g);
  kfc    <<<40,  256, 0, stream>>>(z2g, fcwT, fcb, e_f, e_b);
  kprep  <<<16,  256, 0, stream>>>(e_f, e1w, e1b, e2w, Sg, Vt, c0, P5, P6, W2T0);
  kq3    <<<640, 256, 0, stream>>>(e_f, Sg, e1w, P5, P6, c0, Q3c);
  kh01   <<<dim3(640,2), 256, 0, stream>>>(e_b, Vt, Q3c, si2, sj2, sk2);
  k5a    <<<16,  256, 0, stream>>>(si2, sj2, e2w, e2b, A4, A5, A6, A7);
  k5b    <<<dim3(640,3), 256, 0, stream>>>(si2, sj2, sk2, e2w, A4, A5, A6, A7, A1p, A2t, Cc);
  kh2    <<<640, 256, 0, stream>>>(e_b, Vt, Q3c, W2T0, A1p, A2t, Cc, op);
  k7     <<<1, 64, 0, stream>>>(op, ow, ob, (float*)d_out);
}